// Round 2
// baseline (794.591 us; speedup 1.0000x reference)
//
#include <hip/hip_runtime.h>
#include <hip/hip_bf16.h>
#include <math.h>

#define B_ 2
#define S_ 2048
#define D_ 256
#define QK_ 256
#define H_ 8
#define HD_ 32
#define MLP_ 1024
#define TOPK_ 8
#define R_ 2048
#define MD_ 64
#define MAXN_ 192

__device__ __constant__ float SCALE_ = 0.17677669529663687f;

// ---------------- adj dtype detection ----------------
__global__ void init_flag(int* flag) { *flag = 0; }

__global__ void detect_adj(const unsigned int* __restrict__ adj, int* __restrict__ flag) {
    long g = (long)blockIdx.x * blockDim.x + threadIdx.x;
    long n = (long)R_ * R_ / 4;   // safe under both interpretations
    int found = 0;
    for (long i = g; i < n; i += (long)gridDim.x * blockDim.x) {
        if (adj[i] > 1u) { found = 1; break; }
    }
    if (found) atomicOr(flag, 1);
}

__device__ inline bool adj_on(const void* adj, int isbyte, long idx) {
    if (isbyte) return ((const unsigned char*)adj)[idx] != 0;
    return ((const int*)adj)[idx] != 0;
}

// ---------------- region memory normalize -> transposed nmT[64][2048] ----------------
__global__ void norm_rm(const float* __restrict__ rm, float* __restrict__ nmT) {
    int r = blockIdx.x, t = threadIdx.x;   // 64 threads
    float v = rm[r * MD_ + t];
    float s = v * v;
    for (int o = 32; o > 0; o >>= 1) s += __shfl_down(s, o);
    s = __shfl(s, 0);
    nmT[t * R_ + r] = v / (sqrtf(s) + 1e-8f);
}

// ---------------- top-8 cosine neighbors: 4 regions per block, coalesced nmT reads ----------------
__global__ __launch_bounds__(256) void topk_kernel(const float* __restrict__ nmT,
                                                   int* __restrict__ tk) {
    __shared__ float nmr4[4][MD_];
    __shared__ float sim_lds[4][R_];
    int r0 = blockIdx.x * 4, t = threadIdx.x;
    // load the 4 query rows (transposed gather, tiny)
    {
        int j = t >> 6, d = t & 63;
        nmr4[j][d] = nmT[d * R_ + r0 + j];
    }
    __syncthreads();
    // sims: thread t handles candidates c = t + 256*k2, all 4 regions at once
#pragma unroll
    for (int k2 = 0; k2 < 8; k2++) {
        int c = t + 256 * k2;
        float s0 = 0.f, s1 = 0.f, s2 = 0.f, s3 = 0.f;
#pragma unroll
        for (int d = 0; d < MD_; d++) {
            float col = nmT[d * R_ + c];          // coalesced across lanes
            s0 = fmaf(nmr4[0][d], col, s0);
            s1 = fmaf(nmr4[1][d], col, s1);
            s2 = fmaf(nmr4[2][d], col, s2);
            s3 = fmaf(nmr4[3][d], col, s3);
        }
        sim_lds[0][c] = (c == r0 + 0) ? -INFINITY : s0;
        sim_lds[1][c] = (c == r0 + 1) ? -INFINITY : s1;
        sim_lds[2][c] = (c == r0 + 2) ? -INFINITY : s2;
        sim_lds[3][c] = (c == r0 + 3) ? -INFINITY : s3;
    }
    __syncthreads();
    // wave w selects top-8 for region r0+w via shuffle argmax (no block barriers)
    int w = t >> 6, ln = t & 63;
    int rg = r0 + w;
    for (int it = 0; it < TOPK_; it++) {
        float bv = -INFINITY; int bi = 0x7fffffff;
        for (int k = 0; k < 32; k++) {
            int c = ln + 64 * k;
            float s = sim_lds[w][c];
            if (s > bv) { bv = s; bi = c; }       // ascending c: strict > keeps lowest idx
        }
        for (int o = 32; o > 0; o >>= 1) {
            float ov = __shfl_down(bv, o); int oi = __shfl_down(bi, o);
            if (ov > bv || (ov == bv && oi < bi)) { bv = ov; bi = oi; }
        }
        bi = __shfl(bi, 0);
        if (ln == 0) {
            tk[rg * TOPK_ + it] = bi;
            sim_lds[w][bi] = -INFINITY;
        }
        // lane0's ds_write precedes next-round ds_reads of the same wave (in-order LDS)
    }
}

// ---------------- neighbor list build (adj union topk) ----------------
__global__ __launch_bounds__(256) void build_nbr(const void* __restrict__ adj,
                                                 const int* __restrict__ tk,
                                                 const int* __restrict__ flag,
                                                 int* __restrict__ nbr_idx,
                                                 int* __restrict__ nbr_cnt) {
    __shared__ int cnt;
    int r = blockIdx.x, t = threadIdx.x;
    if (t == 0) cnt = 0;
    __syncthreads();
    int isbyte = *flag;
    for (int c = t; c < S_; c += 256) {
        long idx = (long)r * R_ + c;
        if (adj_on(adj, isbyte, idx)) {
            int p = atomicAdd(&cnt, 1);
            if (p < MAXN_) nbr_idx[r * MAXN_ + p] = c;
        }
    }
    __syncthreads();
    if (t < TOPK_) {
        int c = tk[r * TOPK_ + t];
        long idx = (long)r * R_ + c;
        if (!adj_on(adj, isbyte, idx) && c < S_) {
            int p = atomicAdd(&cnt, 1);
            if (p < MAXN_) nbr_idx[r * MAXN_ + p] = c;
        }
    }
    __syncthreads();
    if (t == 0) nbr_cnt[r] = min(cnt, MAXN_);
}

// ---------------- layernorm (row of 256) ----------------
__global__ __launch_bounds__(256) void ln_kernel(const float* __restrict__ x,
                                                 const float* __restrict__ g,
                                                 const float* __restrict__ b,
                                                 float* __restrict__ y) {
    __shared__ float red[256];
    int row = blockIdx.x, t = threadIdx.x;
    float v = x[(long)row * D_ + t];
    red[t] = v; __syncthreads();
    for (int o = 128; o > 0; o >>= 1) { if (t < o) red[t] += red[t + o]; __syncthreads(); }
    float mean = red[0] / D_;
    __syncthreads();
    float dv = v - mean;
    red[t] = dv * dv; __syncthreads();
    for (int o = 128; o > 0; o >>= 1) { if (t < o) red[t] += red[t + o]; __syncthreads(); }
    float var = red[0] / D_;
    y[(long)row * D_ + t] = dv * rsqrtf(var + 1e-5f) * g[t] + b[t];
}

// ---------------- generic fp32 GEMM: C = A[M,K] @ W[K,N] (+bias)(+accum)(+gelu)(+resid) ----------------
template <int EPI>
__global__ __launch_bounds__(256) void gemm_kernel(const float* __restrict__ A,
                                                   const float* __restrict__ W,
                                                   const float* __restrict__ bias,
                                                   const float* __restrict__ resid,
                                                   float* __restrict__ C,
                                                   int M, int N, int K, int accum) {
    __shared__ float As[16][65];
    __shared__ float Ws[16][64];
    int tid = threadIdx.x;
    int tx = tid & 15, ty = tid >> 4;
    int m0 = blockIdx.y * 64, n0 = blockIdx.x * 64;
    int ac = tid & 15, ar0 = tid >> 4;
    int wc = tid & 63, wr0 = tid >> 6;
    float acc[4][4] = {};
    for (int k0 = 0; k0 < K; k0 += 16) {
#pragma unroll
        for (int qq = 0; qq < 4; qq++) {
            int r = ar0 + 16 * qq;
            As[ac][r] = A[(long)(m0 + r) * K + k0 + ac];
        }
#pragma unroll
        for (int qq = 0; qq < 4; qq++) {
            int kr = wr0 + 4 * qq;
            Ws[kr][wc] = W[(long)(k0 + kr) * N + n0 + wc];
        }
        __syncthreads();
#pragma unroll
        for (int kk = 0; kk < 16; kk++) {
            float a[4], wv[4];
#pragma unroll
            for (int i = 0; i < 4; i++) a[i] = As[kk][ty * 4 + i];
#pragma unroll
            for (int j = 0; j < 4; j++) wv[j] = Ws[kk][tx * 4 + j];
#pragma unroll
            for (int i = 0; i < 4; i++)
#pragma unroll
                for (int j = 0; j < 4; j++)
                    acc[i][j] = fmaf(a[i], wv[j], acc[i][j]);
        }
        __syncthreads();
    }
#pragma unroll
    for (int i = 0; i < 4; i++) {
        int m = m0 + ty * 4 + i;
#pragma unroll
        for (int j = 0; j < 4; j++) {
            int n = n0 + tx * 4 + j;
            float v = acc[i][j];
            if (bias) v += bias[n];
            if (accum) v += C[(long)m * N + n];
            if (EPI == 1) v = 0.5f * v * (1.0f + erff(v * 0.70710678118654752f));
            if (resid) v += resid[(long)m * N + n];
            C[(long)m * N + n] = v;
        }
    }
}

// ---------------- v column sums, two-stage ----------------
__global__ void vsum1(const float* __restrict__ v, float* __restrict__ part) {
    // grid: B_*64 blocks of 256 threads; block = (b, 32-row chunk)
    int b = blockIdx.x >> 6, ch = blockIdx.x & 63;
    int c = threadIdx.x;
    float s = 0.f;
    int j0 = ch * 32;
    for (int j = j0; j < j0 + 32; j++) s += v[((long)b * S_ + j) * QK_ + c];
    part[(long)blockIdx.x * QK_ + c] = s;
}

__global__ void vsum2(const float* __restrict__ part, float* __restrict__ vs) {
    int g = blockIdx.x * 256 + threadIdx.x;   // 0..511
    int b = g >> 8, c = g & 255;
    float s = 0.f;
    for (int ch = 0; ch < 64; ch++) s += part[(long)(b * 64 + ch) * QK_ + c];
    vs[g] = s;
}

// ---------------- sparse attention via neighbor lists ----------------
__global__ __launch_bounds__(256) void attn_kernel(const float* __restrict__ q,
                                                   const float* __restrict__ k,
                                                   const float* __restrict__ v,
                                                   const float* __restrict__ vs,
                                                   const int* __restrict__ ridx,
                                                   const int* __restrict__ nbr_idx,
                                                   const int* __restrict__ nbr_cnt,
                                                   float* __restrict__ out) {
    __shared__ float qs[QK_];
    __shared__ float sj[H_][MAXN_];
    __shared__ int   nb[MAXN_];
    int bi = blockIdx.x;              // b*S + i
    int b = bi / S_, i = bi - b * S_;
    int t = threadIdx.x;
    int h = t >> 5, ln = t & 31;
    int r = ridx[i];
    int cnt = nbr_cnt[r];
    qs[t] = q[(long)bi * QK_ + t];
    for (int p = t; p < cnt; p += 256) nb[p] = nbr_idx[r * MAXN_ + p];
    __syncthreads();
    for (int p = ln; p < cnt; p += 32) {
        int j = nb[p];
        const float* kr = k + ((long)b * S_ + j) * QK_ + h * HD_;
        const float* qh = qs + h * HD_;
        float s = 0.f;
#pragma unroll
        for (int d = 0; d < HD_; d++) s = fmaf(qh[d], kr[d], s);
        sj[h][p] = s * SCALE_;
    }
    __syncthreads();
    float m = 0.0f;
    for (int p = 0; p < cnt; p++) m = fmaxf(m, sj[h][p]);
    float em = expf(-m);
    float Z = (float)(S_ - cnt) * em;
    float accv = 0.f, vn = 0.f;
    int d = ln;
    for (int p = 0; p < cnt; p++) {
        int j = nb[p];
        float vv = v[((long)b * S_ + j) * QK_ + h * HD_ + d];
        float e = expf(sj[h][p] - m);
        Z += e;
        accv = fmaf(e, vv, accv);
        vn += vv;
    }
    float o = (em * (vs[b * QK_ + h * HD_ + d] - vn) + accv) / Z;
    out[(long)bi * QK_ + h * HD_ + d] = o;
}

// ---------------- gate + fuse + LN2 ----------------
__global__ __launch_bounds__(256) void fuse_ln2_kernel(const float* __restrict__ x,
                                                       const float* __restrict__ ao,
                                                       const float* __restrict__ gp,
                                                       const float* __restrict__ g2,
                                                       const float* __restrict__ b2,
                                                       float* __restrict__ fused,
                                                       float* __restrict__ h) {
    __shared__ float red[256];
    int row = blockIdx.x, t = threadIdx.x;
    long idx = (long)row * D_ + t;
    float gate = 1.f / (1.f + expf(-gp[idx]));
    float f = gate * x[idx] + (1.f - gate) * ao[idx];
    fused[idx] = f;
    red[t] = f; __syncthreads();
    for (int o = 128; o > 0; o >>= 1) { if (t < o) red[t] += red[t + o]; __syncthreads(); }
    float mean = red[0] / D_;
    __syncthreads();
    float dv = f - mean;
    red[t] = dv * dv; __syncthreads();
    for (int o = 128; o > 0; o >>= 1) { if (t < o) red[t] += red[t + o]; __syncthreads(); }
    float var = red[0] / D_;
    h[idx] = dv * rsqrtf(var + 1e-5f) * g2[t] + b2[t];
}

extern "C" void kernel_launch(void* const* d_in, const int* in_sizes, int n_in,
                              void* d_out, int out_size, void* d_ws, size_t ws_size,
                              hipStream_t stream) {
    const float* x    = (const float*)d_in[0];
    const int*   ridx = (const int*)d_in[1];
    const void*  adj  = d_in[2];
    const float* rm   = (const float*)d_in[3];
    const float* wq = (const float*)d_in[4],  *bq = (const float*)d_in[5];
    const float* wk = (const float*)d_in[6],  *bk = (const float*)d_in[7];
    const float* wv = (const float*)d_in[8],  *bv = (const float*)d_in[9];
    const float* wo = (const float*)d_in[10], *bo = (const float*)d_in[11];
    const float* ln1g = (const float*)d_in[12], *ln1b = (const float*)d_in[13];
    const float* ln2g = (const float*)d_in[14], *ln2b = (const float*)d_in[15];
    const float* gw  = (const float*)d_in[16], *gb  = (const float*)d_in[17];
    const float* fw1 = (const float*)d_in[18], *fb1 = (const float*)d_in[19];
    const float* fw2 = (const float*)d_in[20], *fb2 = (const float*)d_in[21];
    float* out = (float*)d_out;

    // workspace layout (floats)
    float* wsf     = (float*)d_ws;
    int*   flag    = (int*)d_ws;               // 1 int (padded to 64 floats)
    float* nmT     = wsf + 64;                 // 64*R = 131072 (transposed)
    int*   tk      = (int*)(nmT + 131072);     // R*TOPK = 16384
    int*   nbr_idx = tk + 16384;               // R*MAXN = 393216
    int*   nbr_cnt = nbr_idx + R_ * MAXN_;     // 2048
    float* xn      = (float*)(nbr_cnt + 2048); // 1048576
    float* qb      = xn + 1048576;
    float* kb      = qb + 1048576;
    float* vb      = kb + 1048576;
    float* vs      = vb + 1048576;             // 512
    float* attnO   = vs + 512;                 // 1048576 (pre-wo; reused as gate preact)
    float* attn_out= attnO + 1048576;          // 1048576
    float* fusedb  = attn_out + 1048576;       // 1048576
    float* f1      = fusedb + 1048576;         // B*S*MLP = 4194304
    float* part    = f1;                       // vsum partials overlay f1 (disjoint in time)

    const int MROWS = B_ * S_;                 // 4096

    init_flag<<<1, 1, 0, stream>>>(flag);
    detect_adj<<<256, 256, 0, stream>>>((const unsigned int*)adj, flag);
    norm_rm<<<R_, 64, 0, stream>>>(rm, nmT);
    topk_kernel<<<R_ / 4, 256, 0, stream>>>(nmT, tk);
    build_nbr<<<R_, 256, 0, stream>>>(adj, tk, flag, nbr_idx, nbr_cnt);

    ln_kernel<<<MROWS, 256, 0, stream>>>(x, ln1g, ln1b, xn);

    dim3 gqkv(QK_ / 64, MROWS / 64);
    gemm_kernel<0><<<gqkv, 256, 0, stream>>>(xn, wq, bq, nullptr, qb, MROWS, QK_, D_, 0);
    gemm_kernel<0><<<gqkv, 256, 0, stream>>>(xn, wk, bk, nullptr, kb, MROWS, QK_, D_, 0);
    gemm_kernel<0><<<gqkv, 256, 0, stream>>>(xn, wv, bv, nullptr, vb, MROWS, QK_, D_, 0);

    vsum1<<<B_ * 64, 256, 0, stream>>>(vb, part);
    vsum2<<<2, 256, 0, stream>>>(part, vs);
    attn_kernel<<<MROWS, 256, 0, stream>>>(qb, kb, vb, vs, ridx, nbr_idx, nbr_cnt, attnO);

    dim3 gd(D_ / 64, MROWS / 64);
    gemm_kernel<0><<<gd, 256, 0, stream>>>(attnO, wo, bo, nullptr, attn_out, MROWS, D_, QK_, 0);

    float* gatep = attnO;
    gemm_kernel<0><<<gd, 256, 0, stream>>>(x, gw, gb, nullptr, gatep, MROWS, D_, D_, 0);
    gemm_kernel<0><<<gd, 256, 0, stream>>>(attn_out, gw + (long)D_ * D_, nullptr, nullptr, gatep, MROWS, D_, D_, 1);

    float* hb = xn;  // reuse
    fuse_ln2_kernel<<<MROWS, 256, 0, stream>>>(x, attn_out, gatep, ln2g, ln2b, fusedb, hb);

    dim3 gf1(MLP_ / 64, MROWS / 64);
    gemm_kernel<1><<<gf1, 256, 0, stream>>>(hb, fw1, fb1, nullptr, f1, MROWS, MLP_, D_, 0);
    gemm_kernel<0><<<gd, 256, 0, stream>>>(f1, fw2, fb2, fusedb, out, MROWS, D_, MLP_, 0);
}

// Round 3
// 428.863 us; speedup vs baseline: 1.8528x; 1.8528x over previous
//
#include <hip/hip_runtime.h>
#include <hip/hip_bf16.h>
#include <math.h>

#define B_ 2
#define S_ 2048
#define D_ 256
#define QK_ 256
#define H_ 8
#define HD_ 32
#define MLP_ 1024
#define TOPK_ 8
#define R_ 2048
#define MD_ 64
#define MAXN_ 192

__device__ __constant__ float SCALE_ = 0.17677669529663687f;

// ---------------- adj dtype detection ----------------
__global__ void init_flag(int* flag) { *flag = 0; }

__global__ void detect_adj(const unsigned int* __restrict__ adj, int* __restrict__ flag) {
    long g = (long)blockIdx.x * blockDim.x + threadIdx.x;
    long n = (long)R_ * R_ / 4;   // safe under both interpretations
    int found = 0;
    for (long i = g; i < n; i += (long)gridDim.x * blockDim.x) {
        if (adj[i] > 1u) { found = 1; break; }
    }
    if (found) atomicOr(flag, 1);
}

__device__ inline bool adj_on(const void* adj, int isbyte, long idx) {
    if (isbyte) return ((const unsigned char*)adj)[idx] != 0;
    return ((const int*)adj)[idx] != 0;
}

// ---------------- region memory normalize -> transposed nmT[64][2048] ----------------
__global__ void norm_rm(const float* __restrict__ rm, float* __restrict__ nmT) {
    int r = blockIdx.x, t = threadIdx.x;   // 64 threads
    float v = rm[r * MD_ + t];
    float s = v * v;
    for (int o = 32; o > 0; o >>= 1) s += __shfl_down(s, o);
    s = __shfl(s, 0);
    nmT[t * R_ + r] = v / (sqrtf(s) + 1e-8f);
}

// ---------------- top-8 cosine neighbors: 1 region/block, sims in registers, coalesced nmT ----------------
__global__ __launch_bounds__(256) void topk_kernel(const float* __restrict__ nmT,
                                                   int* __restrict__ tk) {
    __shared__ float redv[4];
    __shared__ int   redi[4];
    __shared__ int   winS;
    int r = blockIdx.x, t = threadIdx.x;
    int w = t >> 6, ln = t & 63;
    // lane ln of every wave holds q[ln] (redundant across waves; tiny gather, once)
    float qv = nmT[ln * R_ + r];
    float simv[8];
#pragma unroll
    for (int k2 = 0; k2 < 8; k2++) simv[k2] = 0.f;
    for (int d = 0; d < MD_; d++) {
        float qd = __shfl(qv, d);                 // broadcast q[d] across the wave
        const float* col = nmT + (long)d * R_;
#pragma unroll
        for (int k2 = 0; k2 < 8; k2++)
            simv[k2] = fmaf(qd, col[t + 256 * k2], simv[k2]);   // coalesced
    }
#pragma unroll
    for (int k2 = 0; k2 < 8; k2++)
        if (t + 256 * k2 == r) simv[k2] = -INFINITY;            // exclude diagonal
    for (int it = 0; it < TOPK_; it++) {
        float bv = -INFINITY; int bi = 0x7fffffff;
#pragma unroll
        for (int k2 = 0; k2 < 8; k2++) {
            int c = t + 256 * k2;
            if (simv[k2] > bv) { bv = simv[k2]; bi = c; }       // ascending c: > keeps lowest idx
        }
#pragma unroll
        for (int o = 32; o > 0; o >>= 1) {
            float ov = __shfl_down(bv, o); int oi = __shfl_down(bi, o);
            if (ov > bv || (ov == bv && oi < bi)) { bv = ov; bi = oi; }
        }
        if (ln == 0) { redv[w] = bv; redi[w] = bi; }
        __syncthreads();
        if (t == 0) {
            float xv = redv[0]; int xi = redi[0];
#pragma unroll
            for (int j = 1; j < 4; j++)
                if (redv[j] > xv || (redv[j] == xv && redi[j] < xi)) { xv = redv[j]; xi = redi[j]; }
            tk[r * TOPK_ + it] = xi;
            winS = xi;
        }
        __syncthreads();
        int win = winS;
        if ((win & 255) == t) {                   // owner invalidates, static indices only
#pragma unroll
            for (int k2 = 0; k2 < 8; k2++)
                if ((win >> 8) == k2) simv[k2] = -INFINITY;
        }
        __syncthreads();
    }
}

// ---------------- neighbor list build (adj union topk) ----------------
__global__ __launch_bounds__(256) void build_nbr(const void* __restrict__ adj,
                                                 const int* __restrict__ tk,
                                                 const int* __restrict__ flag,
                                                 int* __restrict__ nbr_idx,
                                                 int* __restrict__ nbr_cnt) {
    __shared__ int cnt;
    int r = blockIdx.x, t = threadIdx.x;
    if (t == 0) cnt = 0;
    __syncthreads();
    int isbyte = *flag;
    for (int c = t; c < S_; c += 256) {
        long idx = (long)r * R_ + c;
        if (adj_on(adj, isbyte, idx)) {
            int p = atomicAdd(&cnt, 1);
            if (p < MAXN_) nbr_idx[r * MAXN_ + p] = c;
        }
    }
    __syncthreads();
    if (t < TOPK_) {
        int c = tk[r * TOPK_ + t];
        long idx = (long)r * R_ + c;
        if (!adj_on(adj, isbyte, idx) && c < S_) {
            int p = atomicAdd(&cnt, 1);
            if (p < MAXN_) nbr_idx[r * MAXN_ + p] = c;
        }
    }
    __syncthreads();
    if (t == 0) nbr_cnt[r] = min(cnt, MAXN_);
}

// ---------------- layernorm (row of 256) ----------------
__global__ __launch_bounds__(256) void ln_kernel(const float* __restrict__ x,
                                                 const float* __restrict__ g,
                                                 const float* __restrict__ b,
                                                 float* __restrict__ y) {
    __shared__ float red[256];
    int row = blockIdx.x, t = threadIdx.x;
    float v = x[(long)row * D_ + t];
    red[t] = v; __syncthreads();
    for (int o = 128; o > 0; o >>= 1) { if (t < o) red[t] += red[t + o]; __syncthreads(); }
    float mean = red[0] / D_;
    __syncthreads();
    float dv = v - mean;
    red[t] = dv * dv; __syncthreads();
    for (int o = 128; o > 0; o >>= 1) { if (t < o) red[t] += red[t + o]; __syncthreads(); }
    float var = red[0] / D_;
    y[(long)row * D_ + t] = dv * rsqrtf(var + 1e-5f) * g[t] + b[t];
}

// ---------------- generic fp32 GEMM: C = A[M,K] @ W[K,N] (+bias)(+accum)(+gelu)(+resid) ----------------
template <int EPI>
__global__ __launch_bounds__(256) void gemm_kernel(const float* __restrict__ A,
                                                   const float* __restrict__ W,
                                                   const float* __restrict__ bias,
                                                   const float* __restrict__ resid,
                                                   float* __restrict__ C,
                                                   int M, int N, int K, int accum) {
    __shared__ float As[16][65];
    __shared__ float Ws[16][64];
    int tid = threadIdx.x;
    int tx = tid & 15, ty = tid >> 4;
    int m0 = blockIdx.y * 64, n0 = blockIdx.x * 64;
    int ac = tid & 15, ar0 = tid >> 4;
    int wc = tid & 63, wr0 = tid >> 6;
    float acc[4][4] = {};
    for (int k0 = 0; k0 < K; k0 += 16) {
#pragma unroll
        for (int qq = 0; qq < 4; qq++) {
            int r = ar0 + 16 * qq;
            As[ac][r] = A[(long)(m0 + r) * K + k0 + ac];
        }
#pragma unroll
        for (int qq = 0; qq < 4; qq++) {
            int kr = wr0 + 4 * qq;
            Ws[kr][wc] = W[(long)(k0 + kr) * N + n0 + wc];
        }
        __syncthreads();
#pragma unroll
        for (int kk = 0; kk < 16; kk++) {
            float a[4], wv[4];
#pragma unroll
            for (int i = 0; i < 4; i++) a[i] = As[kk][ty * 4 + i];
#pragma unroll
            for (int j = 0; j < 4; j++) wv[j] = Ws[kk][tx * 4 + j];
#pragma unroll
            for (int i = 0; i < 4; i++)
#pragma unroll
                for (int j = 0; j < 4; j++)
                    acc[i][j] = fmaf(a[i], wv[j], acc[i][j]);
        }
        __syncthreads();
    }
#pragma unroll
    for (int i = 0; i < 4; i++) {
        int m = m0 + ty * 4 + i;
#pragma unroll
        for (int j = 0; j < 4; j++) {
            int n = n0 + tx * 4 + j;
            float v = acc[i][j];
            if (bias) v += bias[n];
            if (accum) v += C[(long)m * N + n];
            if (EPI == 1) v = 0.5f * v * (1.0f + erff(v * 0.70710678118654752f));
            if (resid) v += resid[(long)m * N + n];
            C[(long)m * N + n] = v;
        }
    }
}

// ---------------- v column sums, two-stage ----------------
__global__ void vsum1(const float* __restrict__ v, float* __restrict__ part) {
    int b = blockIdx.x >> 6, ch = blockIdx.x & 63;
    int c = threadIdx.x;
    float s = 0.f;
    int j0 = ch * 32;
    for (int j = j0; j < j0 + 32; j++) s += v[((long)b * S_ + j) * QK_ + c];
    part[(long)blockIdx.x * QK_ + c] = s;
}

__global__ void vsum2(const float* __restrict__ part, float* __restrict__ vs) {
    int g = blockIdx.x * 256 + threadIdx.x;   // 0..511
    int b = g >> 8, c = g & 255;
    float s = 0.f;
    for (int ch = 0; ch < 64; ch++) s += part[(long)(b * 64 + ch) * QK_ + c];
    vs[g] = s;
}

// ---------------- sparse attention via neighbor lists ----------------
__global__ __launch_bounds__(256) void attn_kernel(const float* __restrict__ q,
                                                   const float* __restrict__ k,
                                                   const float* __restrict__ v,
                                                   const float* __restrict__ vs,
                                                   const int* __restrict__ ridx,
                                                   const int* __restrict__ nbr_idx,
                                                   const int* __restrict__ nbr_cnt,
                                                   float* __restrict__ out) {
    __shared__ float qs[QK_];
    __shared__ float sj[H_][MAXN_];
    __shared__ int   nb[MAXN_];
    int bi = blockIdx.x;              // b*S + i
    int b = bi / S_, i = bi - b * S_;
    int t = threadIdx.x;
    int h = t >> 5, ln = t & 31;
    int r = ridx[i];
    int cnt = nbr_cnt[r];
    qs[t] = q[(long)bi * QK_ + t];
    for (int p = t; p < cnt; p += 256) nb[p] = nbr_idx[r * MAXN_ + p];
    __syncthreads();
    for (int p = ln; p < cnt; p += 32) {
        int j = nb[p];
        const float* kr = k + ((long)b * S_ + j) * QK_ + h * HD_;
        const float* qh = qs + h * HD_;
        float s = 0.f;
#pragma unroll
        for (int d = 0; d < HD_; d++) s = fmaf(qh[d], kr[d], s);
        sj[h][p] = s * SCALE_;
    }
    __syncthreads();
    float m = 0.0f;
    for (int p = 0; p < cnt; p++) m = fmaxf(m, sj[h][p]);
    float em = expf(-m);
    float Z = (float)(S_ - cnt) * em;
    float accv = 0.f, vn = 0.f;
    int d = ln;
    for (int p = 0; p < cnt; p++) {
        int j = nb[p];
        float vv = v[((long)b * S_ + j) * QK_ + h * HD_ + d];
        float e = expf(sj[h][p] - m);
        Z += e;
        accv = fmaf(e, vv, accv);
        vn += vv;
    }
    float o = (em * (vs[b * QK_ + h * HD_ + d] - vn) + accv) / Z;
    out[(long)bi * QK_ + h * HD_ + d] = o;
}

// ---------------- gate + fuse + LN2 ----------------
__global__ __launch_bounds__(256) void fuse_ln2_kernel(const float* __restrict__ x,
                                                       const float* __restrict__ ao,
                                                       const float* __restrict__ gp,
                                                       const float* __restrict__ g2,
                                                       const float* __restrict__ b2,
                                                       float* __restrict__ fused,
                                                       float* __restrict__ h) {
    __shared__ float red[256];
    int row = blockIdx.x, t = threadIdx.x;
    long idx = (long)row * D_ + t;
    float gate = 1.f / (1.f + expf(-gp[idx]));
    float f = gate * x[idx] + (1.f - gate) * ao[idx];
    fused[idx] = f;
    red[t] = f; __syncthreads();
    for (int o = 128; o > 0; o >>= 1) { if (t < o) red[t] += red[t + o]; __syncthreads(); }
    float mean = red[0] / D_;
    __syncthreads();
    float dv = f - mean;
    red[t] = dv * dv; __syncthreads();
    for (int o = 128; o > 0; o >>= 1) { if (t < o) red[t] += red[t + o]; __syncthreads(); }
    float var = red[0] / D_;
    h[idx] = dv * rsqrtf(var + 1e-5f) * g2[t] + b2[t];
}

extern "C" void kernel_launch(void* const* d_in, const int* in_sizes, int n_in,
                              void* d_out, int out_size, void* d_ws, size_t ws_size,
                              hipStream_t stream) {
    const float* x    = (const float*)d_in[0];
    const int*   ridx = (const int*)d_in[1];
    const void*  adj  = d_in[2];
    const float* rm   = (const float*)d_in[3];
    const float* wq = (const float*)d_in[4],  *bq = (const float*)d_in[5];
    const float* wk = (const float*)d_in[6],  *bk = (const float*)d_in[7];
    const float* wv = (const float*)d_in[8],  *bv = (const float*)d_in[9];
    const float* wo = (const float*)d_in[10], *bo = (const float*)d_in[11];
    const float* ln1g = (const float*)d_in[12], *ln1b = (const float*)d_in[13];
    const float* ln2g = (const float*)d_in[14], *ln2b = (const float*)d_in[15];
    const float* gw  = (const float*)d_in[16], *gb  = (const float*)d_in[17];
    const float* fw1 = (const float*)d_in[18], *fb1 = (const float*)d_in[19];
    const float* fw2 = (const float*)d_in[20], *fb2 = (const float*)d_in[21];
    float* out = (float*)d_out;

    // workspace layout (floats)
    float* wsf     = (float*)d_ws;
    int*   flag    = (int*)d_ws;               // 1 int (padded to 64 floats)
    float* nmT     = wsf + 64;                 // 64*R = 131072 (transposed)
    int*   tk      = (int*)(nmT + 131072);     // R*TOPK = 16384
    int*   nbr_idx = tk + 16384;               // R*MAXN = 393216
    int*   nbr_cnt = nbr_idx + R_ * MAXN_;     // 2048
    float* xn      = (float*)(nbr_cnt + 2048); // 1048576
    float* qb      = xn + 1048576;
    float* kb      = qb + 1048576;
    float* vb      = kb + 1048576;
    float* vs      = vb + 1048576;             // 512
    float* attnO   = vs + 512;                 // 1048576 (pre-wo; reused as gate preact)
    float* attn_out= attnO + 1048576;          // 1048576
    float* fusedb  = attn_out + 1048576;       // 1048576
    float* f1      = fusedb + 1048576;         // B*S*MLP = 4194304
    float* part    = f1;                       // vsum partials overlay f1 (disjoint in time)

    const int MROWS = B_ * S_;                 // 4096

    init_flag<<<1, 1, 0, stream>>>(flag);
    detect_adj<<<256, 256, 0, stream>>>((const unsigned int*)adj, flag);
    norm_rm<<<R_, 64, 0, stream>>>(rm, nmT);
    topk_kernel<<<R_, 256, 0, stream>>>(nmT, tk);
    build_nbr<<<R_, 256, 0, stream>>>(adj, tk, flag, nbr_idx, nbr_cnt);

    ln_kernel<<<MROWS, 256, 0, stream>>>(x, ln1g, ln1b, xn);

    dim3 gqkv(QK_ / 64, MROWS / 64);
    gemm_kernel<0><<<gqkv, 256, 0, stream>>>(xn, wq, bq, nullptr, qb, MROWS, QK_, D_, 0);
    gemm_kernel<0><<<gqkv, 256, 0, stream>>>(xn, wk, bk, nullptr, kb, MROWS, QK_, D_, 0);
    gemm_kernel<0><<<gqkv, 256, 0, stream>>>(xn, wv, bv, nullptr, vb, MROWS, QK_, D_, 0);

    vsum1<<<B_ * 64, 256, 0, stream>>>(vb, part);
    vsum2<<<2, 256, 0, stream>>>(part, vs);
    attn_kernel<<<MROWS, 256, 0, stream>>>(qb, kb, vb, vs, ridx, nbr_idx, nbr_cnt, attnO);

    dim3 gd(D_ / 64, MROWS / 64);
    gemm_kernel<0><<<gd, 256, 0, stream>>>(attnO, wo, bo, nullptr, attn_out, MROWS, D_, QK_, 0);

    float* gatep = attnO;
    gemm_kernel<0><<<gd, 256, 0, stream>>>(x, gw, gb, nullptr, gatep, MROWS, D_, D_, 0);
    gemm_kernel<0><<<gd, 256, 0, stream>>>(attn_out, gw + (long)D_ * D_, nullptr, nullptr, gatep, MROWS, D_, D_, 1);

    float* hb = xn;  // reuse
    fuse_ln2_kernel<<<MROWS, 256, 0, stream>>>(x, attn_out, gatep, ln2g, ln2b, fusedb, hb);

    dim3 gf1(MLP_ / 64, MROWS / 64);
    gemm_kernel<1><<<gf1, 256, 0, stream>>>(hb, fw1, fb1, nullptr, f1, MROWS, MLP_, D_, 0);
    gemm_kernel<0><<<gd, 256, 0, stream>>>(f1, fw2, fb2, fusedb, out, MROWS, D_, MLP_, 0);
}

// Round 4
// 261.670 us; speedup vs baseline: 3.0366x; 1.6389x over previous
//
#include <hip/hip_runtime.h>
#include <hip/hip_bf16.h>
#include <math.h>

#define B_ 2
#define S_ 2048
#define D_ 256
#define QK_ 256
#define H_ 8
#define HD_ 32
#define MLP_ 1024
#define TOPK_ 8
#define R_ 2048
#define MD_ 64
#define MAXN_ 192

using bf16_t = __hip_bfloat16;
using bf16x8 = __attribute__((ext_vector_type(8))) short;   // 8 bf16 (4 VGPRs)
using f32x4  = __attribute__((ext_vector_type(4))) float;   // 4 fp32 acc

__device__ __constant__ float SCALE_ = 0.17677669529663687f;

// ---------------- adj dtype detection ----------------
__global__ void init_flag(int* flag) { *flag = 0; }

__global__ void detect_adj(const unsigned int* __restrict__ adj, int* __restrict__ flag) {
    long g = (long)blockIdx.x * blockDim.x + threadIdx.x;
    long n = (long)R_ * R_ / 4;
    int found = 0;
    for (long i = g; i < n; i += (long)gridDim.x * blockDim.x) {
        if (adj[i] > 1u) { found = 1; break; }
    }
    if (found) atomicOr(flag, 1);
}

__device__ inline bool adj_on(const void* adj, int isbyte, long idx) {
    if (isbyte) return ((const unsigned char*)adj)[idx] != 0;
    return ((const int*)adj)[idx] != 0;
}

// ---------------- region memory normalize -> transposed nmT[64][2048] ----------------
__global__ void norm_rm(const float* __restrict__ rm, float* __restrict__ nmT) {
    int r = blockIdx.x, t = threadIdx.x;   // 64 threads
    float v = rm[r * MD_ + t];
    float s = v * v;
    for (int o = 32; o > 0; o >>= 1) s += __shfl_down(s, o);
    s = __shfl(s, 0);
    nmT[t * R_ + r] = v / (sqrtf(s) + 1e-8f);
}

// ---------------- top-8 cosine neighbors: sims in registers, coalesced nmT ----------------
__global__ __launch_bounds__(256) void topk_kernel(const float* __restrict__ nmT,
                                                   int* __restrict__ tk) {
    __shared__ float redv[4];
    __shared__ int   redi[4];
    __shared__ int   winS;
    int r = blockIdx.x, t = threadIdx.x;
    int w = t >> 6, ln = t & 63;
    float qv = nmT[ln * R_ + r];
    float simv[8];
#pragma unroll
    for (int k2 = 0; k2 < 8; k2++) simv[k2] = 0.f;
    for (int d = 0; d < MD_; d++) {
        float qd = __shfl(qv, d);
        const float* col = nmT + (long)d * R_;
#pragma unroll
        for (int k2 = 0; k2 < 8; k2++)
            simv[k2] = fmaf(qd, col[t + 256 * k2], simv[k2]);
    }
#pragma unroll
    for (int k2 = 0; k2 < 8; k2++)
        if (t + 256 * k2 == r) simv[k2] = -INFINITY;
    for (int it = 0; it < TOPK_; it++) {
        float bv = -INFINITY; int bi = 0x7fffffff;
#pragma unroll
        for (int k2 = 0; k2 < 8; k2++) {
            int c = t + 256 * k2;
            if (simv[k2] > bv) { bv = simv[k2]; bi = c; }
        }
#pragma unroll
        for (int o = 32; o > 0; o >>= 1) {
            float ov = __shfl_down(bv, o); int oi = __shfl_down(bi, o);
            if (ov > bv || (ov == bv && oi < bi)) { bv = ov; bi = oi; }
        }
        if (ln == 0) { redv[w] = bv; redi[w] = bi; }
        __syncthreads();
        if (t == 0) {
            float xv = redv[0]; int xi = redi[0];
#pragma unroll
            for (int j = 1; j < 4; j++)
                if (redv[j] > xv || (redv[j] == xv && redi[j] < xi)) { xv = redv[j]; xi = redi[j]; }
            tk[r * TOPK_ + it] = xi;
            winS = xi;
        }
        __syncthreads();
        int win = winS;
        if ((win & 255) == t) {
#pragma unroll
            for (int k2 = 0; k2 < 8; k2++)
                if ((win >> 8) == k2) simv[k2] = -INFINITY;
        }
        __syncthreads();
    }
}

// ---------------- neighbor list build (adj union topk) ----------------
__global__ __launch_bounds__(256) void build_nbr(const void* __restrict__ adj,
                                                 const int* __restrict__ tk,
                                                 const int* __restrict__ flag,
                                                 int* __restrict__ nbr_idx,
                                                 int* __restrict__ nbr_cnt) {
    __shared__ int cnt;
    int r = blockIdx.x, t = threadIdx.x;
    if (t == 0) cnt = 0;
    __syncthreads();
    int isbyte = *flag;
    for (int c = t; c < S_; c += 256) {
        long idx = (long)r * R_ + c;
        if (adj_on(adj, isbyte, idx)) {
            int p = atomicAdd(&cnt, 1);
            if (p < MAXN_) nbr_idx[r * MAXN_ + p] = c;
        }
    }
    __syncthreads();
    if (t < TOPK_) {
        int c = tk[r * TOPK_ + t];
        long idx = (long)r * R_ + c;
        if (!adj_on(adj, isbyte, idx) && c < S_) {
            int p = atomicAdd(&cnt, 1);
            if (p < MAXN_) nbr_idx[r * MAXN_ + p] = c;
        }
    }
    __syncthreads();
    if (t == 0) nbr_cnt[r] = min(cnt, MAXN_);
}

// ---------------- layernorm (row of 256) -> bf16 out ----------------
__global__ __launch_bounds__(256) void ln_kernel(const float* __restrict__ x,
                                                 const float* __restrict__ g,
                                                 const float* __restrict__ b,
                                                 bf16_t* __restrict__ y) {
    __shared__ float red[256];
    int row = blockIdx.x, t = threadIdx.x;
    float v = x[(long)row * D_ + t];
    red[t] = v; __syncthreads();
    for (int o = 128; o > 0; o >>= 1) { if (t < o) red[t] += red[t + o]; __syncthreads(); }
    float mean = red[0] / D_;
    __syncthreads();
    float dv = v - mean;
    red[t] = dv * dv; __syncthreads();
    for (int o = 128; o > 0; o >>= 1) { if (t < o) red[t] += red[t + o]; __syncthreads(); }
    float var = red[0] / D_;
    y[(long)row * D_ + t] = __float2bfloat16(dv * rsqrtf(var + 1e-5f) * g[t] + b[t]);
}

// ---------------- weight transpose+convert: W[K][N] fp32 -> WT[N][K] bf16 ----------------
__global__ __launch_bounds__(256) void conv_w(const float* w0, const float* w1, const float* w2,
                                              const float* w3, const float* w4, const float* w5,
                                              const float* w6, bf16_t* wt) {
    __shared__ float tile[32][33];
    int tb = blockIdx.x;
    const float* W; long dstoff; int K, N, local;
    if (tb < 64)       { W = w0; dstoff = 0;       K = 256;  N = 256;  local = tb; }
    else if (tb < 128) { W = w1; dstoff = 65536;   K = 256;  N = 256;  local = tb - 64; }
    else if (tb < 192) { W = w2; dstoff = 131072;  K = 256;  N = 256;  local = tb - 128; }
    else if (tb < 256) { W = w3; dstoff = 196608;  K = 256;  N = 256;  local = tb - 192; }
    else if (tb < 384) { W = w4; dstoff = 262144;  K = 512;  N = 256;  local = tb - 256; }
    else if (tb < 640) { W = w5; dstoff = 393216;  K = 256;  N = 1024; local = tb - 384; }
    else               { W = w6; dstoff = 655360;  K = 1024; N = 256;  local = tb - 640; }
    int ntn = N >> 5;
    int tk = local / ntn, tn = local - tk * ntn;
    int k0 = tk * 32, n0 = tn * 32;
    int r = threadIdx.x >> 5, c = threadIdx.x & 31;
#pragma unroll
    for (int rr = 0; rr < 4; rr++)
        tile[r + rr * 8][c] = W[(long)(k0 + r + rr * 8) * N + n0 + c];
    __syncthreads();
    bf16_t* dst = wt + dstoff;
#pragma unroll
    for (int rr = 0; rr < 4; rr++)
        dst[(long)(n0 + r + rr * 8) * K + k0 + c] = __float2bfloat16(tile[c][r + rr * 8]);
}

__global__ void conv_bqkv(const float* bq, const float* bk, const float* bv, float* bqkv) {
    int t = threadIdx.x;  // 768
    bqkv[t] = t < 256 ? bq[t] : (t < 512 ? bk[t - 256] : bv[t - 512]);
}

// x fp32 -> bf16 into xcat cols 0..255 (ld 512)
__global__ __launch_bounds__(256) void conv_x(const float* __restrict__ x, bf16_t* __restrict__ xcat) {
    int row = blockIdx.x, t = threadIdx.x;
    xcat[(long)row * 512 + t] = __float2bfloat16(x[(long)row * 256 + t]);
}

// ---------------- MFMA bf16 GEMM: C = A[M,K] @ WT[N,K]^T ----------------
#define BM 128
#define BN 128
#define BKg 32
#define LDT 40

template<int GELU>
__global__ __launch_bounds__(256) void mgemm(const bf16_t* __restrict__ A,
                                             const bf16_t* __restrict__ Wt,
                                             const float* __restrict__ bias,
                                             const float* __restrict__ resid,
                                             float* __restrict__ Cf,
                                             bf16_t* __restrict__ Cb,
                                             int M, int N, int K, int ldcb) {
    __shared__ short As[BM * LDT];
    __shared__ short Bs[BN * LDT];
    int tid = threadIdx.x;
    int m0 = blockIdx.y * BM, n0 = blockIdx.x * BN;
    int w = tid >> 6, ln = tid & 63;
    int wr = w >> 1, wc = w & 1;
    int srow = tid >> 2, skb = (tid & 3) * 8;
    f32x4 zero4 = {0.f, 0.f, 0.f, 0.f};
    f32x4 acc[4][4];
#pragma unroll
    for (int i = 0; i < 4; i++)
#pragma unroll
        for (int j = 0; j < 4; j++) acc[i][j] = zero4;

    const bf16_t* Ab = A + (long)m0 * K + skb;
    const bf16_t* Bb = Wt + (long)n0 * K + skb;

    for (int k0 = 0; k0 < K; k0 += BKg) {
        uint4 a0 = *(const uint4*)(Ab + (long)srow * K + k0);
        uint4 a1 = *(const uint4*)(Ab + (long)(srow + 64) * K + k0);
        uint4 b0 = *(const uint4*)(Bb + (long)srow * K + k0);
        uint4 b1 = *(const uint4*)(Bb + (long)(srow + 64) * K + k0);
        *(uint4*)(&As[srow * LDT + skb]) = a0;
        *(uint4*)(&As[(srow + 64) * LDT + skb]) = a1;
        *(uint4*)(&Bs[srow * LDT + skb]) = b0;
        *(uint4*)(&Bs[(srow + 64) * LDT + skb]) = b1;
        __syncthreads();
        bf16x8 af[4], bfr[4];
        int kr = (ln >> 4) * 8;
        int arow = wr * 64 + (ln & 15);
        int brow = wc * 64 + (ln & 15);
#pragma unroll
        for (int mi = 0; mi < 4; mi++)
            af[mi] = *(const bf16x8*)(&As[(arow + mi * 16) * LDT + kr]);
#pragma unroll
        for (int ni = 0; ni < 4; ni++)
            bfr[ni] = *(const bf16x8*)(&Bs[(brow + ni * 16) * LDT + kr]);
#pragma unroll
        for (int mi = 0; mi < 4; mi++)
#pragma unroll
            for (int ni = 0; ni < 4; ni++)
                acc[mi][ni] = __builtin_amdgcn_mfma_f32_16x16x32_bf16(af[mi], bfr[ni], acc[mi][ni], 0, 0, 0);
        __syncthreads();
    }
    // epilogue: D[row=(l>>4)*4+r][col=l&15] per 16x16 frag (m89-verified layout)
    int colb = n0 + wc * 64 + (ln & 15);
    int rowb = m0 + wr * 64 + (ln >> 4) * 4;
#pragma unroll
    for (int ni = 0; ni < 4; ni++) {
        int col = colb + ni * 16;
        float bv = bias ? bias[col] : 0.f;
#pragma unroll
        for (int mi = 0; mi < 4; mi++) {
#pragma unroll
            for (int r = 0; r < 4; r++) {
                int row = rowb + mi * 16 + r;
                float v = acc[mi][ni][r] + bv;
                if (GELU) v = 0.5f * v * (1.0f + erff(v * 0.70710678118654752f));
                if (resid) v += resid[(long)row * N + col];
                if (Cf) Cf[(long)row * N + col] = v;
                if (Cb) Cb[(long)row * ldcb + col] = __float2bfloat16(v);
            }
        }
    }
}

// ---------------- v column sums (v = qkv[:, 512:768]), two-stage ----------------
__global__ void vsum1(const float* __restrict__ qkv, float* __restrict__ part) {
    int b = blockIdx.x >> 6, ch = blockIdx.x & 63;
    int c = threadIdx.x;
    float s = 0.f;
    int j0 = ch * 32;
    for (int j = j0; j < j0 + 32; j++) s += qkv[((long)b * S_ + j) * 768 + 512 + c];
    part[(long)blockIdx.x * QK_ + c] = s;
}

__global__ void vsum2(const float* __restrict__ part, float* __restrict__ vs) {
    int g = blockIdx.x * 256 + threadIdx.x;   // 0..511
    int b = g >> 8, c = g & 255;
    float s = 0.f;
    for (int ch = 0; ch < 64; ch++) s += part[(long)(b * 64 + ch) * QK_ + c];
    vs[g] = s;
}

// ---------------- sparse attention via neighbor lists (reads fused qkv, writes bf16) ----------------
__global__ __launch_bounds__(256) void attn_kernel(const float* __restrict__ qkv,
                                                   const float* __restrict__ vs,
                                                   const int* __restrict__ ridx,
                                                   const int* __restrict__ nbr_idx,
                                                   const int* __restrict__ nbr_cnt,
                                                   bf16_t* __restrict__ out) {
    __shared__ float qs[QK_];
    __shared__ float sj[H_][MAXN_];
    __shared__ int   nb[MAXN_];
    int bi = blockIdx.x;              // b*S + i
    int b = bi / S_, i = bi - b * S_;
    int t = threadIdx.x;
    int h = t >> 5, ln = t & 31;
    int r = ridx[i];
    int cnt = nbr_cnt[r];
    qs[t] = qkv[(long)bi * 768 + t];
    for (int p = t; p < cnt; p += 256) nb[p] = nbr_idx[r * MAXN_ + p];
    __syncthreads();
    for (int p = ln; p < cnt; p += 32) {
        int j = nb[p];
        const float* kr = qkv + ((long)b * S_ + j) * 768 + 256 + h * HD_;
        const float* qh = qs + h * HD_;
        float s = 0.f;
#pragma unroll
        for (int d = 0; d < HD_; d++) s = fmaf(qh[d], kr[d], s);
        sj[h][p] = s * SCALE_;
    }
    __syncthreads();
    float m = 0.0f;
    for (int p = 0; p < cnt; p++) m = fmaxf(m, sj[h][p]);
    float em = expf(-m);
    float Z = (float)(S_ - cnt) * em;
    float accv = 0.f, vn = 0.f;
    int d = ln;
    for (int p = 0; p < cnt; p++) {
        int j = nb[p];
        float vv = qkv[((long)b * S_ + j) * 768 + 512 + h * HD_ + d];
        float e = expf(sj[h][p] - m);
        Z += e;
        accv = fmaf(e, vv, accv);
        vn += vv;
    }
    float o = (em * (vs[b * QK_ + h * HD_ + d] - vn) + accv) / Z;
    out[(long)bi * QK_ + h * HD_ + d] = __float2bfloat16(o);
}

// ---------------- gate + fuse + LN2 (writes fused fp32, h bf16) ----------------
__global__ __launch_bounds__(256) void fuse_ln2_kernel(const float* __restrict__ x,
                                                       const float* __restrict__ ao,
                                                       const float* __restrict__ gp,
                                                       const float* __restrict__ g2,
                                                       const float* __restrict__ b2,
                                                       float* __restrict__ fused,
                                                       bf16_t* __restrict__ h) {
    __shared__ float red[256];
    int row = blockIdx.x, t = threadIdx.x;
    long idx = (long)row * D_ + t;
    float gate = 1.f / (1.f + expf(-gp[idx]));
    float f = gate * x[idx] + (1.f - gate) * ao[idx];
    fused[idx] = f;
    red[t] = f; __syncthreads();
    for (int o = 128; o > 0; o >>= 1) { if (t < o) red[t] += red[t + o]; __syncthreads(); }
    float mean = red[0] / D_;
    __syncthreads();
    float dv = f - mean;
    red[t] = dv * dv; __syncthreads();
    for (int o = 128; o > 0; o >>= 1) { if (t < o) red[t] += red[t + o]; __syncthreads(); }
    float var = red[0] / D_;
    h[idx] = __float2bfloat16(dv * rsqrtf(var + 1e-5f) * g2[t] + b2[t]);
}

extern "C" void kernel_launch(void* const* d_in, const int* in_sizes, int n_in,
                              void* d_out, int out_size, void* d_ws, size_t ws_size,
                              hipStream_t stream) {
    const float* x    = (const float*)d_in[0];
    const int*   ridx = (const int*)d_in[1];
    const void*  adj  = d_in[2];
    const float* rm   = (const float*)d_in[3];
    const float* wq = (const float*)d_in[4],  *bq = (const float*)d_in[5];
    const float* wk = (const float*)d_in[6],  *bk = (const float*)d_in[7];
    const float* wv = (const float*)d_in[8],  *bv = (const float*)d_in[9];
    const float* wo = (const float*)d_in[10], *bo = (const float*)d_in[11];
    const float* ln1g = (const float*)d_in[12], *ln1b = (const float*)d_in[13];
    const float* ln2g = (const float*)d_in[14], *ln2b = (const float*)d_in[15];
    const float* gw  = (const float*)d_in[16], *gb  = (const float*)d_in[17];
    const float* fw1 = (const float*)d_in[18], *fb1 = (const float*)d_in[19];
    const float* fw2 = (const float*)d_in[20], *fb2 = (const float*)d_in[21];
    float* out = (float*)d_out;

    // workspace layout (float units; all offsets 16B-aligned)
    float* wsf      = (float*)d_ws;
    int*   flag     = (int*)d_ws;                  // @0 (64)
    float* nmT      = wsf + 64;                    // 131072
    int*   tk       = (int*)(nmT + 131072);        // 16384
    int*   nbr_idx  = tk + 16384;                  // 393216
    int*   nbr_cnt  = nbr_idx + R_ * MAXN_;        // 2048
    float* qkv      = (float*)(nbr_cnt + 2048);    // 4096*768 = 3145728
    float* vs       = qkv + 3145728;               // 512
    float* gatep    = vs + 512;                    // 1048576
    float* attn_out = gatep + 1048576;             // 1048576
    float* fusedb   = attn_out + 1048576;          // 1048576
    float* part     = fusedb + 1048576;            // 32768
    bf16_t* xn_bf   = (bf16_t*)(part + 32768);     // 1048576 bf16 (524288 fl)
    bf16_t* attnO_bf= (bf16_t*)((float*)xn_bf + 524288);    // 1048576 bf16
    bf16_t* xcat_bf = (bf16_t*)((float*)attnO_bf + 524288); // 4096*512 bf16 (1048576 fl)
    bf16_t* hb_bf   = (bf16_t*)((float*)xcat_bf + 1048576); // 1048576 bf16
    bf16_t* f1_bf   = (bf16_t*)((float*)hb_bf + 524288);    // 4096*1024 bf16 (2097152 fl)
    bf16_t* WT      = (bf16_t*)((float*)f1_bf + 2097152);   // 917504 bf16 (458752 fl)
    float* bqkv     = (float*)WT + 458752;         // 768

    const int MROWS = B_ * S_;                     // 4096

    init_flag<<<1, 1, 0, stream>>>(flag);
    detect_adj<<<256, 256, 0, stream>>>((const unsigned int*)adj, flag);
    norm_rm<<<R_, 64, 0, stream>>>(rm, nmT);
    topk_kernel<<<R_, 256, 0, stream>>>(nmT, tk);
    build_nbr<<<R_, 256, 0, stream>>>(adj, tk, flag, nbr_idx, nbr_cnt);

    conv_w<<<896, 256, 0, stream>>>(wq, wk, wv, wo, gw, fw1, fw2, WT);
    conv_bqkv<<<1, 768, 0, stream>>>(bq, bk, bv, bqkv);
    conv_x<<<MROWS, 256, 0, stream>>>(x, xcat_bf);

    ln_kernel<<<MROWS, 256, 0, stream>>>(x, ln1g, ln1b, xn_bf);

    // QKV fused: [4096,256] @ [256,768] -> qkv fp32 [4096][768]
    mgemm<0><<<dim3(768 / BN, MROWS / BM), 256, 0, stream>>>(
        xn_bf, WT + 0, bqkv, nullptr, qkv, nullptr, MROWS, 768, 256, 0);

    vsum1<<<B_ * 64, 256, 0, stream>>>(qkv, part);
    vsum2<<<2, 256, 0, stream>>>(part, vs);
    attn_kernel<<<MROWS, 256, 0, stream>>>(qkv, vs, ridx, nbr_idx, nbr_cnt, attnO_bf);

    // wo: attnO @ wo + bo -> attn_out fp32; bf16 copy into xcat cols 256..511
    mgemm<0><<<dim3(256 / BN, MROWS / BM), 256, 0, stream>>>(
        attnO_bf, WT + 196608, bo, nullptr, attn_out, xcat_bf + 256, MROWS, 256, 256, 512);

    // gate: [x | attn_out] @ gw + gb -> gatep fp32   (K=512)
    mgemm<0><<<dim3(256 / BN, MROWS / BM), 256, 0, stream>>>(
        xcat_bf, WT + 262144, gb, nullptr, gatep, nullptr, MROWS, 256, 512, 0);

    fuse_ln2_kernel<<<MROWS, 256, 0, stream>>>(x, attn_out, gatep, ln2g, ln2b, fusedb, hb_bf);

    // FFN1: h @ w1 + b1, gelu -> f1 bf16
    mgemm<1><<<dim3(1024 / BN, MROWS / BM), 256, 0, stream>>>(
        hb_bf, WT + 393216, fb1, nullptr, nullptr, f1_bf, MROWS, 1024, 256, 1024);

    // FFN2: f1 @ w2 + b2 + fused -> out fp32
    mgemm<0><<<dim3(256 / BN, MROWS / BM), 256, 0, stream>>>(
        f1_bf, WT + 655360, fb2, fusedb, out, nullptr, MROWS, 256, 1024, 0);
}

// Round 5
// 231.029 us; speedup vs baseline: 3.4394x; 1.1326x over previous
//
#include <hip/hip_runtime.h>
#include <hip/hip_bf16.h>
#include <math.h>

#define B_ 2
#define S_ 2048
#define D_ 256
#define QK_ 256
#define H_ 8
#define HD_ 32
#define MLP_ 1024
#define TOPK_ 8
#define R_ 2048
#define MD_ 64
#define MAXN_ 192

using bf16_t = __hip_bfloat16;
using bf16x8 = __attribute__((ext_vector_type(8))) short;   // 8 bf16 (4 VGPRs)
using f32x4  = __attribute__((ext_vector_type(4))) float;   // 4 fp32 acc

__device__ __constant__ float SCALE_ = 0.17677669529663687f;

// ---------------- adj dtype detection ----------------
__global__ void init_flag(int* flag) { *flag = 0; }

__global__ void detect_adj(const unsigned int* __restrict__ adj, int* __restrict__ flag) {
    long g = (long)blockIdx.x * blockDim.x + threadIdx.x;
    long n = (long)R_ * R_ / 4;
    int found = 0;
    for (long i = g; i < n; i += (long)gridDim.x * blockDim.x) {
        if (adj[i] > 1u) { found = 1; break; }
    }
    if (found) atomicOr(flag, 1);
}

__device__ inline bool adj_on(const void* adj, int isbyte, long idx) {
    if (isbyte) return ((const unsigned char*)adj)[idx] != 0;
    return ((const int*)adj)[idx] != 0;
}

// ---------------- region memory normalize -> transposed nmT[64][2048] ----------------
__global__ void norm_rm(const float* __restrict__ rm, float* __restrict__ nmT) {
    int r = blockIdx.x, t = threadIdx.x;   // 64 threads
    float v = rm[r * MD_ + t];
    float s = v * v;
    for (int o = 32; o > 0; o >>= 1) s += __shfl_down(s, o);
    s = __shfl(s, 0);
    nmT[t * R_ + r] = v / (sqrtf(s) + 1e-8f);
}

// ---------------- top-8 cosine neighbors: sims in registers, coalesced nmT ----------------
__global__ __launch_bounds__(256) void topk_kernel(const float* __restrict__ nmT,
                                                   int* __restrict__ tk) {
    __shared__ float redv[4];
    __shared__ int   redi[4];
    __shared__ int   winS;
    int r = blockIdx.x, t = threadIdx.x;
    int w = t >> 6, ln = t & 63;
    float qv = nmT[ln * R_ + r];
    float simv[8];
#pragma unroll
    for (int k2 = 0; k2 < 8; k2++) simv[k2] = 0.f;
    for (int d = 0; d < MD_; d++) {
        float qd = __shfl(qv, d);
        const float* col = nmT + (long)d * R_;
#pragma unroll
        for (int k2 = 0; k2 < 8; k2++)
            simv[k2] = fmaf(qd, col[t + 256 * k2], simv[k2]);
    }
#pragma unroll
    for (int k2 = 0; k2 < 8; k2++)
        if (t + 256 * k2 == r) simv[k2] = -INFINITY;
    for (int it = 0; it < TOPK_; it++) {
        float bv = -INFINITY; int bi = 0x7fffffff;
#pragma unroll
        for (int k2 = 0; k2 < 8; k2++) {
            int c = t + 256 * k2;
            if (simv[k2] > bv) { bv = simv[k2]; bi = c; }
        }
#pragma unroll
        for (int o = 32; o > 0; o >>= 1) {
            float ov = __shfl_down(bv, o); int oi = __shfl_down(bi, o);
            if (ov > bv || (ov == bv && oi < bi)) { bv = ov; bi = oi; }
        }
        if (ln == 0) { redv[w] = bv; redi[w] = bi; }
        __syncthreads();
        if (t == 0) {
            float xv = redv[0]; int xi = redi[0];
#pragma unroll
            for (int j = 1; j < 4; j++)
                if (redv[j] > xv || (redv[j] == xv && redi[j] < xi)) { xv = redv[j]; xi = redi[j]; }
            tk[r * TOPK_ + it] = xi;
            winS = xi;
        }
        __syncthreads();
        int win = winS;
        if ((win & 255) == t) {
#pragma unroll
            for (int k2 = 0; k2 < 8; k2++)
                if ((win >> 8) == k2) simv[k2] = -INFINITY;
        }
        __syncthreads();
    }
}

// ---------------- neighbor list build (adj union topk) ----------------
__global__ __launch_bounds__(256) void build_nbr(const void* __restrict__ adj,
                                                 const int* __restrict__ tk,
                                                 const int* __restrict__ flag,
                                                 int* __restrict__ nbr_idx,
                                                 int* __restrict__ nbr_cnt) {
    __shared__ int cnt;
    int r = blockIdx.x, t = threadIdx.x;
    if (t == 0) cnt = 0;
    __syncthreads();
    int isbyte = *flag;
    for (int c = t; c < S_; c += 256) {
        long idx = (long)r * R_ + c;
        if (adj_on(adj, isbyte, idx)) {
            int p = atomicAdd(&cnt, 1);
            if (p < MAXN_) nbr_idx[r * MAXN_ + p] = c;
        }
    }
    __syncthreads();
    if (t < TOPK_) {
        int c = tk[r * TOPK_ + t];
        long idx = (long)r * R_ + c;
        if (!adj_on(adj, isbyte, idx) && c < S_) {
            int p = atomicAdd(&cnt, 1);
            if (p < MAXN_) nbr_idx[r * MAXN_ + p] = c;
        }
    }
    __syncthreads();
    if (t == 0) nbr_cnt[r] = min(cnt, MAXN_);
}

// ---------------- layernorm (row of 256) -> bf16 out ----------------
__global__ __launch_bounds__(256) void ln_kernel(const float* __restrict__ x,
                                                 const float* __restrict__ g,
                                                 const float* __restrict__ b,
                                                 bf16_t* __restrict__ y) {
    __shared__ float red[256];
    int row = blockIdx.x, t = threadIdx.x;
    float v = x[(long)row * D_ + t];
    red[t] = v; __syncthreads();
    for (int o = 128; o > 0; o >>= 1) { if (t < o) red[t] += red[t + o]; __syncthreads(); }
    float mean = red[0] / D_;
    __syncthreads();
    float dv = v - mean;
    red[t] = dv * dv; __syncthreads();
    for (int o = 128; o > 0; o >>= 1) { if (t < o) red[t] += red[t + o]; __syncthreads(); }
    float var = red[0] / D_;
    y[(long)row * D_ + t] = __float2bfloat16(dv * rsqrtf(var + 1e-5f) * g[t] + b[t]);
}

// ---------------- weight transpose+convert: W[K][N] fp32 -> WT[N][K] bf16 ----------------
__global__ __launch_bounds__(256) void conv_w(const float* w0, const float* w1, const float* w2,
                                              const float* w3, const float* w4, const float* w5,
                                              const float* w6, bf16_t* wt) {
    __shared__ float tile[32][33];
    int tb = blockIdx.x;
    const float* W; long dstoff; int K, N, local;
    if (tb < 64)       { W = w0; dstoff = 0;       K = 256;  N = 256;  local = tb; }
    else if (tb < 128) { W = w1; dstoff = 65536;   K = 256;  N = 256;  local = tb - 64; }
    else if (tb < 192) { W = w2; dstoff = 131072;  K = 256;  N = 256;  local = tb - 128; }
    else if (tb < 256) { W = w3; dstoff = 196608;  K = 256;  N = 256;  local = tb - 192; }
    else if (tb < 384) { W = w4; dstoff = 262144;  K = 512;  N = 256;  local = tb - 256; }
    else if (tb < 640) { W = w5; dstoff = 393216;  K = 256;  N = 1024; local = tb - 384; }
    else               { W = w6; dstoff = 655360;  K = 1024; N = 256;  local = tb - 640; }
    int ntn = N >> 5;
    int tk = local / ntn, tn = local - tk * ntn;
    int k0 = tk * 32, n0 = tn * 32;
    int r = threadIdx.x >> 5, c = threadIdx.x & 31;
#pragma unroll
    for (int rr = 0; rr < 4; rr++)
        tile[r + rr * 8][c] = W[(long)(k0 + r + rr * 8) * N + n0 + c];
    __syncthreads();
    bf16_t* dst = wt + dstoff;
#pragma unroll
    for (int rr = 0; rr < 4; rr++)
        dst[(long)(n0 + r + rr * 8) * K + k0 + c] = __float2bfloat16(tile[c][r + rr * 8]);
}

__global__ void conv_bqkv(const float* bq, const float* bk, const float* bv, float* bqkv) {
    int t = threadIdx.x;  // 768
    bqkv[t] = t < 256 ? bq[t] : (t < 512 ? bk[t - 256] : bv[t - 512]);
}

// x fp32 -> bf16 into xcat cols 0..255 (ld 512)
__global__ __launch_bounds__(256) void conv_x(const float* __restrict__ x, bf16_t* __restrict__ xcat) {
    int row = blockIdx.x, t = threadIdx.x;
    xcat[(long)row * 512 + t] = __float2bfloat16(x[(long)row * 256 + t]);
}

// ---------------- MFMA bf16 GEMM: C = A[M,K] @ WT[N,K]^T ----------------
#define BM 128
#define BN 128
#define BKg 32
#define LDT 40

template<int GELU>
__global__ __launch_bounds__(256) void mgemm(const bf16_t* __restrict__ A,
                                             const bf16_t* __restrict__ Wt,
                                             const float* __restrict__ bias,
                                             const float* __restrict__ resid,
                                             float* __restrict__ Cf,
                                             bf16_t* __restrict__ Cb,
                                             int M, int N, int K, int ldcb) {
    __shared__ short As[BM * LDT];
    __shared__ short Bs[BN * LDT];
    int tid = threadIdx.x;
    int m0 = blockIdx.y * BM, n0 = blockIdx.x * BN;
    int w = tid >> 6, ln = tid & 63;
    int wr = w >> 1, wc = w & 1;
    int srow = tid >> 2, skb = (tid & 3) * 8;
    f32x4 zero4 = {0.f, 0.f, 0.f, 0.f};
    f32x4 acc[4][4];
#pragma unroll
    for (int i = 0; i < 4; i++)
#pragma unroll
        for (int j = 0; j < 4; j++) acc[i][j] = zero4;

    const bf16_t* Ab = A + (long)m0 * K + skb;
    const bf16_t* Bb = Wt + (long)n0 * K + skb;

    for (int k0 = 0; k0 < K; k0 += BKg) {
        uint4 a0 = *(const uint4*)(Ab + (long)srow * K + k0);
        uint4 a1 = *(const uint4*)(Ab + (long)(srow + 64) * K + k0);
        uint4 b0 = *(const uint4*)(Bb + (long)srow * K + k0);
        uint4 b1 = *(const uint4*)(Bb + (long)(srow + 64) * K + k0);
        *(uint4*)(&As[srow * LDT + skb]) = a0;
        *(uint4*)(&As[(srow + 64) * LDT + skb]) = a1;
        *(uint4*)(&Bs[srow * LDT + skb]) = b0;
        *(uint4*)(&Bs[(srow + 64) * LDT + skb]) = b1;
        __syncthreads();
        bf16x8 af[4], bfr[4];
        int kr = (ln >> 4) * 8;
        int arow = wr * 64 + (ln & 15);
        int brow = wc * 64 + (ln & 15);
#pragma unroll
        for (int mi = 0; mi < 4; mi++)
            af[mi] = *(const bf16x8*)(&As[(arow + mi * 16) * LDT + kr]);
#pragma unroll
        for (int ni = 0; ni < 4; ni++)
            bfr[ni] = *(const bf16x8*)(&Bs[(brow + ni * 16) * LDT + kr]);
#pragma unroll
        for (int mi = 0; mi < 4; mi++)
#pragma unroll
            for (int ni = 0; ni < 4; ni++)
                acc[mi][ni] = __builtin_amdgcn_mfma_f32_16x16x32_bf16(af[mi], bfr[ni], acc[mi][ni], 0, 0, 0);
        __syncthreads();
    }
    // epilogue: D[row=(l>>4)*4+r][col=l&15] per 16x16 frag (m89-verified layout)
    int colb = n0 + wc * 64 + (ln & 15);
    int rowb = m0 + wr * 64 + (ln >> 4) * 4;
#pragma unroll
    for (int ni = 0; ni < 4; ni++) {
        int col = colb + ni * 16;
        float bv = bias ? bias[col] : 0.f;
#pragma unroll
        for (int mi = 0; mi < 4; mi++) {
#pragma unroll
            for (int r = 0; r < 4; r++) {
                int row = rowb + mi * 16 + r;
                float v = acc[mi][ni][r] + bv;
                if (GELU) v = 0.5f * v * (1.0f + erff(v * 0.70710678118654752f));
                if (resid) v += resid[(long)row * N + col];
                if (Cf) Cf[(long)row * N + col] = v;
                if (Cb) Cb[(long)row * ldcb + col] = __float2bfloat16(v);
            }
        }
    }
}

// ---------------- v column sums (v = qkv[:, 512:768]), two-stage ----------------
__global__ void vsum1(const float* __restrict__ qkv, float* __restrict__ part) {
    int b = blockIdx.x >> 6, ch = blockIdx.x & 63;
    int c = threadIdx.x;
    float s = 0.f;
    int j0 = ch * 32;
    for (int j = j0; j < j0 + 32; j++) s += qkv[((long)b * S_ + j) * 768 + 512 + c];
    part[(long)blockIdx.x * QK_ + c] = s;
}

__global__ void vsum2(const float* __restrict__ part, float* __restrict__ vs) {
    int g = blockIdx.x * 256 + threadIdx.x;   // 0..511
    int b = g >> 8, c = g & 255;
    float s = 0.f;
    for (int ch = 0; ch < 64; ch++) s += part[(long)(b * 64 + ch) * QK_ + c];
    vs[g] = s;
}

// ---------------- sparse attention: wave-parallel softmax, exp-once, reg scores ----------------
__global__ __launch_bounds__(256) void attn_kernel(const float* __restrict__ qkv,
                                                   const float* __restrict__ vs,
                                                   const int* __restrict__ ridx,
                                                   const int* __restrict__ nbr_idx,
                                                   const int* __restrict__ nbr_cnt,
                                                   bf16_t* __restrict__ out) {
    __shared__ float qs[QK_];
    __shared__ float ej[H_][MAXN_];
    __shared__ int   nb[MAXN_];
    int bi = blockIdx.x;              // b*S + i
    int b = bi >> 11, i = bi & (S_ - 1);
    int t = threadIdx.x;
    int h = t >> 5, ln = t & 31;
    int r = ridx[i];
    int cnt = nbr_cnt[r];
    qs[t] = qkv[(long)bi * 768 + t];
    for (int p = t; p < cnt; p += 256) nb[p] = nbr_idx[r * MAXN_ + p];
    __syncthreads();
    const float4* qh4 = (const float4*)(qs + h * HD_);
    const float* kvb = qkv + (long)b * S_ * 768;
    // pass 1: lane ln owns neighbors p = ln + 32*u (u<6); scores in registers, float4 K loads
    float sreg[6];
    float lmax = 0.0f;                // masked zeros always present (cnt << S)
#pragma unroll
    for (int u = 0; u < 6; u++) {
        int p = ln + 32 * u;
        sreg[u] = 0.f;
        if (p < cnt) {
            int j = nb[p];
            const float4* kr4 = (const float4*)(kvb + (long)j * 768 + 256 + h * HD_);
            float s = 0.f;
#pragma unroll
            for (int dd = 0; dd < 8; dd++) {
                float4 k4 = kr4[dd];
                float4 q4 = qh4[dd];
                s = fmaf(q4.x, k4.x, s);
                s = fmaf(q4.y, k4.y, s);
                s = fmaf(q4.z, k4.z, s);
                s = fmaf(q4.w, k4.w, s);
            }
            s *= SCALE_;
            sreg[u] = s;
            lmax = fmaxf(lmax, s);
        }
    }
    // head-group max (width-32 butterfly)
#pragma unroll
    for (int o = 16; o > 0; o >>= 1) lmax = fmaxf(lmax, __shfl_xor(lmax, o, 32));
    // exp once per neighbor (owner lane), local Z
    float lz = 0.f;
#pragma unroll
    for (int u = 0; u < 6; u++) {
        int p = ln + 32 * u;
        if (p < cnt) {
            float e = expf(sreg[u] - lmax);
            ej[h][p] = e;
            lz += e;
        }
    }
#pragma unroll
    for (int o = 16; o > 0; o >>= 1) lz += __shfl_xor(lz, o, 32);
    float em = expf(-lmax);
    float Z = lz + (float)(S_ - cnt) * em;
    // V accumulation: lane = output dim d; ej reads are same-address broadcast.
    // ej written/read by the same wave -> no block barrier needed.
    float accv = 0.f, vn = 0.f;
    const float* vbase = kvb + 512 + h * HD_ + ln;
#pragma unroll 4
    for (int p = 0; p < cnt; p++) {
        int j = nb[p];
        float vv = vbase[(long)j * 768];
        float e = ej[h][p];
        accv = fmaf(e, vv, accv);
        vn += vv;
    }
    float o = (em * (vs[b * QK_ + h * HD_ + ln] - vn) + accv) / Z;
    out[(long)bi * QK_ + h * HD_ + ln] = __float2bfloat16(o);
}

// ---------------- gate + fuse + LN2 (writes fused fp32, h bf16) ----------------
__global__ __launch_bounds__(256) void fuse_ln2_kernel(const float* __restrict__ x,
                                                       const float* __restrict__ ao,
                                                       const float* __restrict__ gp,
                                                       const float* __restrict__ g2,
                                                       const float* __restrict__ b2,
                                                       float* __restrict__ fused,
                                                       bf16_t* __restrict__ h) {
    __shared__ float red[256];
    int row = blockIdx.x, t = threadIdx.x;
    long idx = (long)row * D_ + t;
    float gate = 1.f / (1.f + expf(-gp[idx]));
    float f = gate * x[idx] + (1.f - gate) * ao[idx];
    fused[idx] = f;
    red[t] = f; __syncthreads();
    for (int o = 128; o > 0; o >>= 1) { if (t < o) red[t] += red[t + o]; __syncthreads(); }
    float mean = red[0] / D_;
    __syncthreads();
    float dv = f - mean;
    red[t] = dv * dv; __syncthreads();
    for (int o = 128; o > 0; o >>= 1) { if (t < o) red[t] += red[t + o]; __syncthreads(); }
    float var = red[0] / D_;
    h[idx] = __float2bfloat16(dv * rsqrtf(var + 1e-5f) * g2[t] + b2[t]);
}

extern "C" void kernel_launch(void* const* d_in, const int* in_sizes, int n_in,
                              void* d_out, int out_size, void* d_ws, size_t ws_size,
                              hipStream_t stream) {
    const float* x    = (const float*)d_in[0];
    const int*   ridx = (const int*)d_in[1];
    const void*  adj  = d_in[2];
    const float* rm   = (const float*)d_in[3];
    const float* wq = (const float*)d_in[4],  *bq = (const float*)d_in[5];
    const float* wk = (const float*)d_in[6],  *bk = (const float*)d_in[7];
    const float* wv = (const float*)d_in[8],  *bv = (const float*)d_in[9];
    const float* wo = (const float*)d_in[10], *bo = (const float*)d_in[11];
    const float* ln1g = (const float*)d_in[12], *ln1b = (const float*)d_in[13];
    const float* ln2g = (const float*)d_in[14], *ln2b = (const float*)d_in[15];
    const float* gw  = (const float*)d_in[16], *gb  = (const float*)d_in[17];
    const float* fw1 = (const float*)d_in[18], *fb1 = (const float*)d_in[19];
    const float* fw2 = (const float*)d_in[20], *fb2 = (const float*)d_in[21];
    float* out = (float*)d_out;

    // workspace layout (float units; all offsets 16B-aligned)
    float* wsf      = (float*)d_ws;
    int*   flag     = (int*)d_ws;                  // @0 (64)
    float* nmT      = wsf + 64;                    // 131072
    int*   tk       = (int*)(nmT + 131072);        // 16384
    int*   nbr_idx  = tk + 16384;                  // 393216
    int*   nbr_cnt  = nbr_idx + R_ * MAXN_;        // 2048
    float* qkv      = (float*)(nbr_cnt + 2048);    // 4096*768 = 3145728
    float* vs       = qkv + 3145728;               // 512
    float* gatep    = vs + 512;                    // 1048576
    float* attn_out = gatep + 1048576;             // 1048576
    float* fusedb   = attn_out + 1048576;          // 1048576
    float* part     = fusedb + 1048576;            // 32768
    bf16_t* xn_bf   = (bf16_t*)(part + 32768);     // 1048576 bf16 (524288 fl)
    bf16_t* attnO_bf= (bf16_t*)((float*)xn_bf + 524288);    // 1048576 bf16
    bf16_t* xcat_bf = (bf16_t*)((float*)attnO_bf + 524288); // 4096*512 bf16 (1048576 fl)
    bf16_t* hb_bf   = (bf16_t*)((float*)xcat_bf + 1048576); // 1048576 bf16
    bf16_t* f1_bf   = (bf16_t*)((float*)hb_bf + 524288);    // 4096*1024 bf16 (2097152 fl)
    bf16_t* WT      = (bf16_t*)((float*)f1_bf + 2097152);   // 917504 bf16 (458752 fl)
    float* bqkv     = (float*)WT + 458752;         // 768

    const int MROWS = B_ * S_;                     // 4096

    init_flag<<<1, 1, 0, stream>>>(flag);
    detect_adj<<<256, 256, 0, stream>>>((const unsigned int*)adj, flag);
    norm_rm<<<R_, 64, 0, stream>>>(rm, nmT);
    topk_kernel<<<R_, 256, 0, stream>>>(nmT, tk);
    build_nbr<<<R_, 256, 0, stream>>>(adj, tk, flag, nbr_idx, nbr_cnt);

    conv_w<<<896, 256, 0, stream>>>(wq, wk, wv, wo, gw, fw1, fw2, WT);
    conv_bqkv<<<1, 768, 0, stream>>>(bq, bk, bv, bqkv);
    conv_x<<<MROWS, 256, 0, stream>>>(x, xcat_bf);

    ln_kernel<<<MROWS, 256, 0, stream>>>(x, ln1g, ln1b, xn_bf);

    // QKV fused: [4096,256] @ [256,768] -> qkv fp32 [4096][768]
    mgemm<0><<<dim3(768 / BN, MROWS / BM), 256, 0, stream>>>(
        xn_bf, WT + 0, bqkv, nullptr, qkv, nullptr, MROWS, 768, 256, 0);

    vsum1<<<B_ * 64, 256, 0, stream>>>(qkv, part);
    vsum2<<<2, 256, 0, stream>>>(part, vs);
    attn_kernel<<<MROWS, 256, 0, stream>>>(qkv, vs, ridx, nbr_idx, nbr_cnt, attnO_bf);

    // wo: attnO @ wo + bo -> attn_out fp32; bf16 copy into xcat cols 256..511
    mgemm<0><<<dim3(256 / BN, MROWS / BM), 256, 0, stream>>>(
        attnO_bf, WT + 196608, bo, nullptr, attn_out, xcat_bf + 256, MROWS, 256, 256, 512);

    // gate: [x | attn_out] @ gw + gb -> gatep fp32   (K=512)
    mgemm<0><<<dim3(256 / BN, MROWS / BM), 256, 0, stream>>>(
        xcat_bf, WT + 262144, gb, nullptr, gatep, nullptr, MROWS, 256, 512, 0);

    fuse_ln2_kernel<<<MROWS, 256, 0, stream>>>(x, attn_out, gatep, ln2g, ln2b, fusedb, hb_bf);

    // FFN1: h @ w1 + b1, gelu -> f1 bf16
    mgemm<1><<<dim3(1024 / BN, MROWS / BM), 256, 0, stream>>>(
        hb_bf, WT + 393216, fb1, nullptr, nullptr, f1_bf, MROWS, 1024, 256, 1024);

    // FFN2: f1 @ w2 + b2 + fused -> out fp32
    mgemm<0><<<dim3(256 / BN, MROWS / BM), 256, 0, stream>>>(
        f1_bf, WT + 655360, fb2, fusedb, out, nullptr, MROWS, 256, 1024, 0);
}

// Round 6
// 224.358 us; speedup vs baseline: 3.5416x; 1.0297x over previous
//
#include <hip/hip_runtime.h>
#include <hip/hip_bf16.h>
#include <math.h>

#define B_ 2
#define S_ 2048
#define D_ 256
#define QK_ 256
#define H_ 8
#define HD_ 32
#define MLP_ 1024
#define TOPK_ 8
#define R_ 2048
#define MD_ 64
#define MAXN_ 192

using bf16_t = __hip_bfloat16;
using bf16x8 = __attribute__((ext_vector_type(8))) short;   // 8 bf16 (4 VGPRs)
using f32x4  = __attribute__((ext_vector_type(4))) float;   // 4 fp32 acc

__device__ __constant__ float SCALE_ = 0.17677669529663687f;

// ---------------- adj dtype detection ----------------
__global__ void init_flag(int* flag) { *flag = 0; }

__global__ void detect_adj(const unsigned int* __restrict__ adj, int* __restrict__ flag) {
    long g = (long)blockIdx.x * blockDim.x + threadIdx.x;
    long n = (long)R_ * R_ / 4;
    int found = 0;
    for (long i = g; i < n; i += (long)gridDim.x * blockDim.x) {
        if (adj[i] > 1u) { found = 1; break; }
    }
    if (found) atomicOr(flag, 1);
}

__device__ inline bool adj_on(const void* adj, int isbyte, long idx) {
    if (isbyte) return ((const unsigned char*)adj)[idx] != 0;
    return ((const int*)adj)[idx] != 0;
}

// ---------------- region memory normalize -> transposed nmT[64][2048] ----------------
__global__ void norm_rm(const float* __restrict__ rm, float* __restrict__ nmT) {
    int r = blockIdx.x, t = threadIdx.x;   // 64 threads
    float v = rm[r * MD_ + t];
    float s = v * v;
    for (int o = 32; o > 0; o >>= 1) s += __shfl_down(s, o);
    s = __shfl(s, 0);
    nmT[t * R_ + r] = v / (sqrtf(s) + 1e-8f);
}

// ---------------- top-8 cosine neighbors: 4 regions/block, float4 loads, reg sims ----------------
__global__ __launch_bounds__(256) void topk_kernel(const float* __restrict__ nmT,
                                                   int* __restrict__ tk) {
    __shared__ float qs[4][MD_];
    __shared__ float redv[4][4];
    __shared__ int   redi[4][4];
    __shared__ int   winS[4];
    int r0 = blockIdx.x * 4, t = threadIdx.x;
    int w = t >> 6, ln = t & 63;
    // stage the 4 query rows into LDS: qs[w][ln] (one gather load per thread)
    qs[w][ln] = nmT[ln * R_ + r0 + w];
    __syncthreads();

    float simv[4][8];
#pragma unroll
    for (int rr = 0; rr < 4; rr++)
#pragma unroll
        for (int k = 0; k < 8; k++) simv[rr][k] = 0.f;

    const float* colbase = nmT + 8 * t;      // thread owns candidates 8t..8t+7
    for (int d0 = 0; d0 < MD_; d0 += 4) {
        float4 q4[4];
#pragma unroll
        for (int rr = 0; rr < 4; rr++) q4[rr] = *(const float4*)(&qs[rr][d0]);
#pragma unroll
        for (int dd = 0; dd < 4; dd++) {
            const float4* c4 = (const float4*)(colbase + (long)(d0 + dd) * R_);
            float4 x0 = c4[0], x1 = c4[1];
#pragma unroll
            for (int rr = 0; rr < 4; rr++) {
                float qd = dd == 0 ? q4[rr].x : dd == 1 ? q4[rr].y : dd == 2 ? q4[rr].z : q4[rr].w;
                simv[rr][0] = fmaf(qd, x0.x, simv[rr][0]);
                simv[rr][1] = fmaf(qd, x0.y, simv[rr][1]);
                simv[rr][2] = fmaf(qd, x0.z, simv[rr][2]);
                simv[rr][3] = fmaf(qd, x0.w, simv[rr][3]);
                simv[rr][4] = fmaf(qd, x1.x, simv[rr][4]);
                simv[rr][5] = fmaf(qd, x1.y, simv[rr][5]);
                simv[rr][6] = fmaf(qd, x1.z, simv[rr][6]);
                simv[rr][7] = fmaf(qd, x1.w, simv[rr][7]);
            }
        }
    }
    // diagonal exclusion: candidate c == r0+rr
#pragma unroll
    for (int rr = 0; rr < 4; rr++) {
        int c = r0 + rr;
        if ((c >> 3) == t) {
#pragma unroll
            for (int k = 0; k < 8; k++)
                if ((c & 7) == k) simv[rr][k] = -INFINITY;
        }
    }
    // 8 extraction rounds; 2 barriers each
    for (int it = 0; it < TOPK_; it++) {
#pragma unroll
        for (int rr = 0; rr < 4; rr++) {
            float bv = -INFINITY; int bi = 0x7fffffff;
#pragma unroll
            for (int k = 0; k < 8; k++) {
                int c = 8 * t + k;
                if (simv[rr][k] > bv) { bv = simv[rr][k]; bi = c; }  // ascending: > keeps lowest
            }
#pragma unroll
            for (int o = 32; o > 0; o >>= 1) {
                float ov = __shfl_down(bv, o); int oi = __shfl_down(bi, o);
                if (ov > bv || (ov == bv && oi < bi)) { bv = ov; bi = oi; }
            }
            if (ln == 0) { redv[rr][w] = bv; redi[rr][w] = bi; }
        }
        __syncthreads();
        if (t < 4) {    // thread t finalizes region t (LDS dynamic index OK)
            float xv = redv[t][0]; int xi = redi[t][0];
#pragma unroll
            for (int j = 1; j < 4; j++)
                if (redv[t][j] > xv || (redv[t][j] == xv && redi[t][j] < xi)) { xv = redv[t][j]; xi = redi[t][j]; }
            tk[(r0 + t) * TOPK_ + it] = xi;
            winS[t] = xi;
        }
        __syncthreads();
#pragma unroll
        for (int rr = 0; rr < 4; rr++) {
            int win = winS[rr];
            if ((win >> 3) == t) {
#pragma unroll
                for (int k = 0; k < 8; k++)
                    if ((win & 7) == k) simv[rr][k] = -INFINITY;
            }
        }
    }
}

// ---------------- neighbor list build (adj union topk) ----------------
__global__ __launch_bounds__(256) void build_nbr(const void* __restrict__ adj,
                                                 const int* __restrict__ tk,
                                                 const int* __restrict__ flag,
                                                 int* __restrict__ nbr_idx,
                                                 int* __restrict__ nbr_cnt) {
    __shared__ int cnt;
    int r = blockIdx.x, t = threadIdx.x;
    if (t == 0) cnt = 0;
    __syncthreads();
    int isbyte = *flag;
    for (int c = t; c < S_; c += 256) {
        long idx = (long)r * R_ + c;
        if (adj_on(adj, isbyte, idx)) {
            int p = atomicAdd(&cnt, 1);
            if (p < MAXN_) nbr_idx[r * MAXN_ + p] = c;
        }
    }
    __syncthreads();
    if (t < TOPK_) {
        int c = tk[r * TOPK_ + t];
        long idx = (long)r * R_ + c;
        if (!adj_on(adj, isbyte, idx) && c < S_) {
            int p = atomicAdd(&cnt, 1);
            if (p < MAXN_) nbr_idx[r * MAXN_ + p] = c;
        }
    }
    __syncthreads();
    if (t == 0) nbr_cnt[r] = min(cnt, MAXN_);
}

// ---------------- layernorm (row of 256) -> bf16 out ----------------
__global__ __launch_bounds__(256) void ln_kernel(const float* __restrict__ x,
                                                 const float* __restrict__ g,
                                                 const float* __restrict__ b,
                                                 bf16_t* __restrict__ y) {
    __shared__ float red[256];
    int row = blockIdx.x, t = threadIdx.x;
    float v = x[(long)row * D_ + t];
    red[t] = v; __syncthreads();
    for (int o = 128; o > 0; o >>= 1) { if (t < o) red[t] += red[t + o]; __syncthreads(); }
    float mean = red[0] / D_;
    __syncthreads();
    float dv = v - mean;
    red[t] = dv * dv; __syncthreads();
    for (int o = 128; o > 0; o >>= 1) { if (t < o) red[t] += red[t + o]; __syncthreads(); }
    float var = red[0] / D_;
    y[(long)row * D_ + t] = __float2bfloat16(dv * rsqrtf(var + 1e-5f) * g[t] + b[t]);
}

// ---------------- weight transpose+convert: W[K][N] fp32 -> WT[N][K] bf16 ----------------
__global__ __launch_bounds__(256) void conv_w(const float* w0, const float* w1, const float* w2,
                                              const float* w3, const float* w4, const float* w5,
                                              const float* w6, bf16_t* wt) {
    __shared__ float tile[32][33];
    int tb = blockIdx.x;
    const float* W; long dstoff; int K, N, local;
    if (tb < 64)       { W = w0; dstoff = 0;       K = 256;  N = 256;  local = tb; }
    else if (tb < 128) { W = w1; dstoff = 65536;   K = 256;  N = 256;  local = tb - 64; }
    else if (tb < 192) { W = w2; dstoff = 131072;  K = 256;  N = 256;  local = tb - 128; }
    else if (tb < 256) { W = w3; dstoff = 196608;  K = 256;  N = 256;  local = tb - 192; }
    else if (tb < 384) { W = w4; dstoff = 262144;  K = 512;  N = 256;  local = tb - 256; }
    else if (tb < 640) { W = w5; dstoff = 393216;  K = 256;  N = 1024; local = tb - 384; }
    else               { W = w6; dstoff = 655360;  K = 1024; N = 256;  local = tb - 640; }
    int ntn = N >> 5;
    int tk = local / ntn, tn = local - tk * ntn;
    int k0 = tk * 32, n0 = tn * 32;
    int r = threadIdx.x >> 5, c = threadIdx.x & 31;
#pragma unroll
    for (int rr = 0; rr < 4; rr++)
        tile[r + rr * 8][c] = W[(long)(k0 + r + rr * 8) * N + n0 + c];
    __syncthreads();
    bf16_t* dst = wt + dstoff;
#pragma unroll
    for (int rr = 0; rr < 4; rr++)
        dst[(long)(n0 + r + rr * 8) * K + k0 + c] = __float2bfloat16(tile[c][r + rr * 8]);
}

__global__ void conv_bqkv(const float* bq, const float* bk, const float* bv, float* bqkv) {
    int t = threadIdx.x;  // 768
    bqkv[t] = t < 256 ? bq[t] : (t < 512 ? bk[t - 256] : bv[t - 512]);
}

// x fp32 -> bf16 into xcat cols 0..255 (ld 512)
__global__ __launch_bounds__(256) void conv_x(const float* __restrict__ x, bf16_t* __restrict__ xcat) {
    int row = blockIdx.x, t = threadIdx.x;
    xcat[(long)row * 512 + t] = __float2bfloat16(x[(long)row * 256 + t]);
}

// ---------------- MFMA bf16 GEMM: C = A[M,K] @ WT[N,K]^T ----------------
#define BM 128
#define BN 128
#define BKg 32
#define LDT 40

template<int GELU>
__global__ __launch_bounds__(256) void mgemm(const bf16_t* __restrict__ A,
                                             const bf16_t* __restrict__ Wt,
                                             const float* __restrict__ bias,
                                             const float* __restrict__ resid,
                                             float* __restrict__ Cf,
                                             bf16_t* __restrict__ Cb,
                                             int M, int N, int K, int ldcb) {
    __shared__ short As[BM * LDT];
    __shared__ short Bs[BN * LDT];
    int tid = threadIdx.x;
    int m0 = blockIdx.y * BM, n0 = blockIdx.x * BN;
    int w = tid >> 6, ln = tid & 63;
    int wr = w >> 1, wc = w & 1;
    int srow = tid >> 2, skb = (tid & 3) * 8;
    f32x4 zero4 = {0.f, 0.f, 0.f, 0.f};
    f32x4 acc[4][4];
#pragma unroll
    for (int i = 0; i < 4; i++)
#pragma unroll
        for (int j = 0; j < 4; j++) acc[i][j] = zero4;

    const bf16_t* Ab = A + (long)m0 * K + skb;
    const bf16_t* Bb = Wt + (long)n0 * K + skb;

    for (int k0 = 0; k0 < K; k0 += BKg) {
        uint4 a0 = *(const uint4*)(Ab + (long)srow * K + k0);
        uint4 a1 = *(const uint4*)(Ab + (long)(srow + 64) * K + k0);
        uint4 b0 = *(const uint4*)(Bb + (long)srow * K + k0);
        uint4 b1 = *(const uint4*)(Bb + (long)(srow + 64) * K + k0);
        *(uint4*)(&As[srow * LDT + skb]) = a0;
        *(uint4*)(&As[(srow + 64) * LDT + skb]) = a1;
        *(uint4*)(&Bs[srow * LDT + skb]) = b0;
        *(uint4*)(&Bs[(srow + 64) * LDT + skb]) = b1;
        __syncthreads();
        bf16x8 af[4], bfr[4];
        int kr = (ln >> 4) * 8;
        int arow = wr * 64 + (ln & 15);
        int brow = wc * 64 + (ln & 15);
#pragma unroll
        for (int mi = 0; mi < 4; mi++)
            af[mi] = *(const bf16x8*)(&As[(arow + mi * 16) * LDT + kr]);
#pragma unroll
        for (int ni = 0; ni < 4; ni++)
            bfr[ni] = *(const bf16x8*)(&Bs[(brow + ni * 16) * LDT + kr]);
#pragma unroll
        for (int mi = 0; mi < 4; mi++)
#pragma unroll
            for (int ni = 0; ni < 4; ni++)
                acc[mi][ni] = __builtin_amdgcn_mfma_f32_16x16x32_bf16(af[mi], bfr[ni], acc[mi][ni], 0, 0, 0);
        __syncthreads();
    }
    // epilogue: D[row=(l>>4)*4+r][col=l&15] per 16x16 frag (m89-verified layout)
    int colb = n0 + wc * 64 + (ln & 15);
    int rowb = m0 + wr * 64 + (ln >> 4) * 4;
#pragma unroll
    for (int ni = 0; ni < 4; ni++) {
        int col = colb + ni * 16;
        float bv = bias ? bias[col] : 0.f;
#pragma unroll
        for (int mi = 0; mi < 4; mi++) {
#pragma unroll
            for (int r = 0; r < 4; r++) {
                int row = rowb + mi * 16 + r;
                float v = acc[mi][ni][r] + bv;
                if (GELU) v = 0.5f * v * (1.0f + erff(v * 0.70710678118654752f));
                if (resid) v += resid[(long)row * N + col];
                if (Cf) Cf[(long)row * N + col] = v;
                if (Cb) Cb[(long)row * ldcb + col] = __float2bfloat16(v);
            }
        }
    }
}

// ---------------- v column sums (v = qkv[:, 512:768]), two-stage ----------------
__global__ void vsum1(const float* __restrict__ qkv, float* __restrict__ part) {
    int b = blockIdx.x >> 6, ch = blockIdx.x & 63;
    int c = threadIdx.x;
    float s = 0.f;
    int j0 = ch * 32;
    for (int j = j0; j < j0 + 32; j++) s += qkv[((long)b * S_ + j) * 768 + 512 + c];
    part[(long)blockIdx.x * QK_ + c] = s;
}

__global__ void vsum2(const float* __restrict__ part, float* __restrict__ vs) {
    int g = blockIdx.x * 256 + threadIdx.x;   // 0..511
    int b = g >> 8, c = g & 255;
    float s = 0.f;
    for (int ch = 0; ch < 64; ch++) s += part[(long)(b * 64 + ch) * QK_ + c];
    vs[g] = s;
}

// ---------------- sparse attention: wave-parallel softmax, exp-once, reg scores ----------------
__global__ __launch_bounds__(256) void attn_kernel(const float* __restrict__ qkv,
                                                   const float* __restrict__ vs,
                                                   const int* __restrict__ ridx,
                                                   const int* __restrict__ nbr_idx,
                                                   const int* __restrict__ nbr_cnt,
                                                   bf16_t* __restrict__ out) {
    __shared__ float qs[QK_];
    __shared__ float ej[H_][MAXN_];
    __shared__ int   nb[MAXN_];
    int bi = blockIdx.x;              // b*S + i
    int b = bi >> 11, i = bi & (S_ - 1);
    int t = threadIdx.x;
    int h = t >> 5, ln = t & 31;
    int r = ridx[i];
    int cnt = nbr_cnt[r];
    qs[t] = qkv[(long)bi * 768 + t];
    for (int p = t; p < cnt; p += 256) nb[p] = nbr_idx[r * MAXN_ + p];
    __syncthreads();
    const float4* qh4 = (const float4*)(qs + h * HD_);
    const float* kvb = qkv + (long)b * S_ * 768;
    float sreg[6];
    float lmax = 0.0f;                // masked zeros always present (cnt << S)
#pragma unroll
    for (int u = 0; u < 6; u++) {
        int p = ln + 32 * u;
        sreg[u] = 0.f;
        if (p < cnt) {
            int j = nb[p];
            const float4* kr4 = (const float4*)(kvb + (long)j * 768 + 256 + h * HD_);
            float s = 0.f;
#pragma unroll
            for (int dd = 0; dd < 8; dd++) {
                float4 k4 = kr4[dd];
                float4 q4 = qh4[dd];
                s = fmaf(q4.x, k4.x, s);
                s = fmaf(q4.y, k4.y, s);
                s = fmaf(q4.z, k4.z, s);
                s = fmaf(q4.w, k4.w, s);
            }
            s *= SCALE_;
            sreg[u] = s;
            lmax = fmaxf(lmax, s);
        }
    }
#pragma unroll
    for (int o = 16; o > 0; o >>= 1) lmax = fmaxf(lmax, __shfl_xor(lmax, o, 32));
    float lz = 0.f;
#pragma unroll
    for (int u = 0; u < 6; u++) {
        int p = ln + 32 * u;
        if (p < cnt) {
            float e = expf(sreg[u] - lmax);
            ej[h][p] = e;
            lz += e;
        }
    }
#pragma unroll
    for (int o = 16; o > 0; o >>= 1) lz += __shfl_xor(lz, o, 32);
    float em = expf(-lmax);
    float Z = lz + (float)(S_ - cnt) * em;
    float accv = 0.f, vn = 0.f;
    const float* vbase = kvb + 512 + h * HD_ + ln;
#pragma unroll 4
    for (int p = 0; p < cnt; p++) {
        int j = nb[p];
        float vv = vbase[(long)j * 768];
        float e = ej[h][p];
        accv = fmaf(e, vv, accv);
        vn += vv;
    }
    float o = (em * (vs[b * QK_ + h * HD_ + ln] - vn) + accv) / Z;
    out[(long)bi * QK_ + h * HD_ + ln] = __float2bfloat16(o);
}

// ---------------- gate + fuse + LN2 (writes fused fp32, h bf16) ----------------
__global__ __launch_bounds__(256) void fuse_ln2_kernel(const float* __restrict__ x,
                                                       const float* __restrict__ ao,
                                                       const float* __restrict__ gp,
                                                       const float* __restrict__ g2,
                                                       const float* __restrict__ b2,
                                                       float* __restrict__ fused,
                                                       bf16_t* __restrict__ h) {
    __shared__ float red[256];
    int row = blockIdx.x, t = threadIdx.x;
    long idx = (long)row * D_ + t;
    float gate = 1.f / (1.f + expf(-gp[idx]));
    float f = gate * x[idx] + (1.f - gate) * ao[idx];
    fused[idx] = f;
    red[t] = f; __syncthreads();
    for (int o = 128; o > 0; o >>= 1) { if (t < o) red[t] += red[t + o]; __syncthreads(); }
    float mean = red[0] / D_;
    __syncthreads();
    float dv = f - mean;
    red[t] = dv * dv; __syncthreads();
    for (int o = 128; o > 0; o >>= 1) { if (t < o) red[t] += red[t + o]; __syncthreads(); }
    float var = red[0] / D_;
    h[idx] = __float2bfloat16(dv * rsqrtf(var + 1e-5f) * g2[t] + b2[t]);
}

extern "C" void kernel_launch(void* const* d_in, const int* in_sizes, int n_in,
                              void* d_out, int out_size, void* d_ws, size_t ws_size,
                              hipStream_t stream) {
    const float* x    = (const float*)d_in[0];
    const int*   ridx = (const int*)d_in[1];
    const void*  adj  = d_in[2];
    const float* rm   = (const float*)d_in[3];
    const float* wq = (const float*)d_in[4],  *bq = (const float*)d_in[5];
    const float* wk = (const float*)d_in[6],  *bk = (const float*)d_in[7];
    const float* wv = (const float*)d_in[8],  *bv = (const float*)d_in[9];
    const float* wo = (const float*)d_in[10], *bo = (const float*)d_in[11];
    const float* ln1g = (const float*)d_in[12], *ln1b = (const float*)d_in[13];
    const float* ln2g = (const float*)d_in[14], *ln2b = (const float*)d_in[15];
    const float* gw  = (const float*)d_in[16], *gb  = (const float*)d_in[17];
    const float* fw1 = (const float*)d_in[18], *fb1 = (const float*)d_in[19];
    const float* fw2 = (const float*)d_in[20], *fb2 = (const float*)d_in[21];
    float* out = (float*)d_out;

    // workspace layout (float units; all offsets 16B-aligned)
    float* wsf      = (float*)d_ws;
    int*   flag     = (int*)d_ws;                  // @0 (64)
    float* nmT      = wsf + 64;                    // 131072
    int*   tk       = (int*)(nmT + 131072);        // 16384
    int*   nbr_idx  = tk + 16384;                  // 393216
    int*   nbr_cnt  = nbr_idx + R_ * MAXN_;        // 2048
    float* qkv      = (float*)(nbr_cnt + 2048);    // 4096*768 = 3145728
    float* vs       = qkv + 3145728;               // 512
    float* gatep    = vs + 512;                    // 1048576
    float* attn_out = gatep + 1048576;             // 1048576
    float* fusedb   = attn_out + 1048576;          // 1048576
    float* part     = fusedb + 1048576;            // 32768
    bf16_t* xn_bf   = (bf16_t*)(part + 32768);     // 1048576 bf16 (524288 fl)
    bf16_t* attnO_bf= (bf16_t*)((float*)xn_bf + 524288);    // 1048576 bf16
    bf16_t* xcat_bf = (bf16_t*)((float*)attnO_bf + 524288); // 4096*512 bf16 (1048576 fl)
    bf16_t* hb_bf   = (bf16_t*)((float*)xcat_bf + 1048576); // 1048576 bf16
    bf16_t* f1_bf   = (bf16_t*)((float*)hb_bf + 524288);    // 4096*1024 bf16 (2097152 fl)
    bf16_t* WT      = (bf16_t*)((float*)f1_bf + 2097152);   // 917504 bf16 (458752 fl)
    float* bqkv     = (float*)WT + 458752;         // 768

    const int MROWS = B_ * S_;                     // 4096

    init_flag<<<1, 1, 0, stream>>>(flag);
    detect_adj<<<256, 256, 0, stream>>>((const unsigned int*)adj, flag);
    norm_rm<<<R_, 64, 0, stream>>>(rm, nmT);
    topk_kernel<<<R_ / 4, 256, 0, stream>>>(nmT, tk);
    build_nbr<<<R_, 256, 0, stream>>>(adj, tk, flag, nbr_idx, nbr_cnt);

    conv_w<<<896, 256, 0, stream>>>(wq, wk, wv, wo, gw, fw1, fw2, WT);
    conv_bqkv<<<1, 768, 0, stream>>>(bq, bk, bv, bqkv);
    conv_x<<<MROWS, 256, 0, stream>>>(x, xcat_bf);

    ln_kernel<<<MROWS, 256, 0, stream>>>(x, ln1g, ln1b, xn_bf);

    // QKV fused: [4096,256] @ [256,768] -> qkv fp32 [4096][768]
    mgemm<0><<<dim3(768 / BN, MROWS / BM), 256, 0, stream>>>(
        xn_bf, WT + 0, bqkv, nullptr, qkv, nullptr, MROWS, 768, 256, 0);

    vsum1<<<B_ * 64, 256, 0, stream>>>(qkv, part);
    vsum2<<<2, 256, 0, stream>>>(part, vs);
    attn_kernel<<<MROWS, 256, 0, stream>>>(qkv, vs, ridx, nbr_idx, nbr_cnt, attnO_bf);

    // wo: attnO @ wo + bo -> attn_out fp32; bf16 copy into xcat cols 256..511
    mgemm<0><<<dim3(256 / BN, MROWS / BM), 256, 0, stream>>>(
        attnO_bf, WT + 196608, bo, nullptr, attn_out, xcat_bf + 256, MROWS, 256, 256, 512);

    // gate: [x | attn_out] @ gw + gb -> gatep fp32   (K=512)
    mgemm<0><<<dim3(256 / BN, MROWS / BM), 256, 0, stream>>>(
        xcat_bf, WT + 262144, gb, nullptr, gatep, nullptr, MROWS, 256, 512, 0);

    fuse_ln2_kernel<<<MROWS, 256, 0, stream>>>(x, attn_out, gatep, ln2g, ln2b, fusedb, hb_bf);

    // FFN1: h @ w1 + b1, gelu -> f1 bf16
    mgemm<1><<<dim3(1024 / BN, MROWS / BM), 256, 0, stream>>>(
        hb_bf, WT + 393216, fb1, nullptr, nullptr, f1_bf, MROWS, 1024, 256, 1024);

    // FFN2: f1 @ w2 + b2 + fused -> out fp32
    mgemm<0><<<dim3(256 / BN, MROWS / BM), 256, 0, stream>>>(
        f1_bf, WT + 655360, fb2, fusedb, out, nullptr, MROWS, 256, 1024, 0);
}

// Round 7
// 170.402 us; speedup vs baseline: 4.6630x; 1.3166x over previous
//
#include <hip/hip_runtime.h>
#include <hip/hip_bf16.h>
#include <math.h>

#define B_ 2
#define S_ 2048
#define D_ 256
#define QK_ 256
#define H_ 8
#define HD_ 32
#define MLP_ 1024
#define TOPK_ 8
#define R_ 2048
#define MD_ 64
#define MAXN_ 192

using bf16_t = __hip_bfloat16;
using bf16x8 = __attribute__((ext_vector_type(8))) short;   // 8 bf16 (4 VGPRs)
using f32x4  = __attribute__((ext_vector_type(4))) float;   // 4 fp32 acc

__device__ __constant__ float SCALE_ = 0.17677669529663687f;

// ---------------- adj dtype detection ----------------
__global__ void init_flag(int* flag) { *flag = 0; }

__global__ void detect_adj(const unsigned int* __restrict__ adj, int* __restrict__ flag) {
    long g = (long)blockIdx.x * blockDim.x + threadIdx.x;
    long n = (long)R_ * R_ / 4;
    int found = 0;
    for (long i = g; i < n; i += (long)gridDim.x * blockDim.x) {
        if (adj[i] > 1u) { found = 1; break; }
    }
    if (found) atomicOr(flag, 1);
}

__device__ inline bool adj_on(const void* adj, int isbyte, long idx) {
    if (isbyte) return ((const unsigned char*)adj)[idx] != 0;
    return ((const int*)adj)[idx] != 0;
}

// ---------------- region memory normalize -> transposed nmT[64][2048] ----------------
__global__ void norm_rm(const float* __restrict__ rm, float* __restrict__ nmT) {
    int r = blockIdx.x, t = threadIdx.x;   // 64 threads
    float v = rm[r * MD_ + t];
    float s = v * v;
    for (int o = 32; o > 0; o >>= 1) s += __shfl_down(s, o);
    s = __shfl(s, 0);
    nmT[t * R_ + r] = v / (sqrtf(s) + 1e-8f);
}

// ---------------- top-8: 2 regions/block (1024 blocks), 1 barrier/round ----------------
__global__ __launch_bounds__(256) void topk_kernel(const float* __restrict__ nmT,
                                                   int* __restrict__ tk) {
    __shared__ float qs[2][MD_];
    __shared__ float redv[2][2][4];   // [buf][region][wave]
    __shared__ int   redi[2][2][4];
    int r0 = blockIdx.x * 2, t = threadIdx.x;
    int w = t >> 6, ln = t & 63;
    if (t < 128) qs[t >> 6][t & 63] = nmT[(t & 63) * R_ + r0 + (t >> 6)];
    __syncthreads();

    float simv[2][8];
#pragma unroll
    for (int rr = 0; rr < 2; rr++)
#pragma unroll
        for (int k = 0; k < 8; k++) simv[rr][k] = 0.f;

    const float* colbase = nmT + 8 * t;      // thread owns candidates 8t..8t+7
    for (int d0 = 0; d0 < MD_; d0 += 4) {
        float4 qa = *(const float4*)(&qs[0][d0]);
        float4 qb = *(const float4*)(&qs[1][d0]);
#pragma unroll
        for (int dd = 0; dd < 4; dd++) {
            const float4* c4 = (const float4*)(colbase + (long)(d0 + dd) * R_);
            float4 x0 = c4[0], x1 = c4[1];
            float q0 = dd == 0 ? qa.x : dd == 1 ? qa.y : dd == 2 ? qa.z : qa.w;
            float q1 = dd == 0 ? qb.x : dd == 1 ? qb.y : dd == 2 ? qb.z : qb.w;
            simv[0][0] = fmaf(q0, x0.x, simv[0][0]); simv[1][0] = fmaf(q1, x0.x, simv[1][0]);
            simv[0][1] = fmaf(q0, x0.y, simv[0][1]); simv[1][1] = fmaf(q1, x0.y, simv[1][1]);
            simv[0][2] = fmaf(q0, x0.z, simv[0][2]); simv[1][2] = fmaf(q1, x0.z, simv[1][2]);
            simv[0][3] = fmaf(q0, x0.w, simv[0][3]); simv[1][3] = fmaf(q1, x0.w, simv[1][3]);
            simv[0][4] = fmaf(q0, x1.x, simv[0][4]); simv[1][4] = fmaf(q1, x1.x, simv[1][4]);
            simv[0][5] = fmaf(q0, x1.y, simv[0][5]); simv[1][5] = fmaf(q1, x1.y, simv[1][5]);
            simv[0][6] = fmaf(q0, x1.z, simv[0][6]); simv[1][6] = fmaf(q1, x1.z, simv[1][6]);
            simv[0][7] = fmaf(q0, x1.w, simv[0][7]); simv[1][7] = fmaf(q1, x1.w, simv[1][7]);
        }
    }
    // diagonal exclusion
#pragma unroll
    for (int rr = 0; rr < 2; rr++) {
        int c = r0 + rr;
        if ((c >> 3) == t) {
#pragma unroll
            for (int k = 0; k < 8; k++)
                if ((c & 7) == k) simv[rr][k] = -INFINITY;
        }
    }
    // 8 extraction rounds; ONE barrier each (double-buffered partials)
    for (int it = 0; it < TOPK_; it++) {
        int buf = it & 1;
#pragma unroll
        for (int rr = 0; rr < 2; rr++) {
            float bv = -INFINITY; int bi = 0x7fffffff;
#pragma unroll
            for (int k = 0; k < 8; k++) {
                int c = 8 * t + k;
                if (simv[rr][k] > bv) { bv = simv[rr][k]; bi = c; }  // ascending: > keeps lowest
            }
#pragma unroll
            for (int o = 32; o > 0; o >>= 1) {
                float ov = __shfl_down(bv, o); int oi = __shfl_down(bi, o);
                if (ov > bv || (ov == bv && oi < bi)) { bv = ov; bi = oi; }
            }
            if (ln == 0) { redv[buf][rr][w] = bv; redi[buf][rr][w] = bi; }
        }
        __syncthreads();
#pragma unroll
        for (int rr = 0; rr < 2; rr++) {
            // every thread redundantly computes the winner (deterministic)
            float xv = redv[buf][rr][0]; int xi = redi[buf][rr][0];
#pragma unroll
            for (int j = 1; j < 4; j++)
                if (redv[buf][rr][j] > xv || (redv[buf][rr][j] == xv && redi[buf][rr][j] < xi)) {
                    xv = redv[buf][rr][j]; xi = redi[buf][rr][j];
                }
            if (t == 0) tk[(r0 + rr) * TOPK_ + it] = xi;
            if ((xi >> 3) == t) {
#pragma unroll
                for (int k = 0; k < 8; k++)
                    if ((xi & 7) == k) simv[rr][k] = -INFINITY;
            }
        }
    }
}

// ---------------- neighbor list build (adj union topk) ----------------
__global__ __launch_bounds__(256) void build_nbr(const void* __restrict__ adj,
                                                 const int* __restrict__ tk,
                                                 const int* __restrict__ flag,
                                                 int* __restrict__ nbr_idx,
                                                 int* __restrict__ nbr_cnt) {
    __shared__ int cnt;
    int r = blockIdx.x, t = threadIdx.x;
    if (t == 0) cnt = 0;
    __syncthreads();
    int isbyte = *flag;
    for (int c = t; c < S_; c += 256) {
        long idx = (long)r * R_ + c;
        if (adj_on(adj, isbyte, idx)) {
            int p = atomicAdd(&cnt, 1);
            if (p < MAXN_) nbr_idx[r * MAXN_ + p] = c;
        }
    }
    __syncthreads();
    if (t < TOPK_) {
        int c = tk[r * TOPK_ + t];
        long idx = (long)r * R_ + c;
        if (!adj_on(adj, isbyte, idx) && c < S_) {
            int p = atomicAdd(&cnt, 1);
            if (p < MAXN_) nbr_idx[r * MAXN_ + p] = c;
        }
    }
    __syncthreads();
    if (t == 0) nbr_cnt[r] = min(cnt, MAXN_);
}

// ---------------- layernorm (row of 256) -> bf16 out ----------------
__global__ __launch_bounds__(256) void ln_kernel(const float* __restrict__ x,
                                                 const float* __restrict__ g,
                                                 const float* __restrict__ b,
                                                 bf16_t* __restrict__ y) {
    __shared__ float red[256];
    int row = blockIdx.x, t = threadIdx.x;
    float v = x[(long)row * D_ + t];
    red[t] = v; __syncthreads();
    for (int o = 128; o > 0; o >>= 1) { if (t < o) red[t] += red[t + o]; __syncthreads(); }
    float mean = red[0] / D_;
    __syncthreads();
    float dv = v - mean;
    red[t] = dv * dv; __syncthreads();
    for (int o = 128; o > 0; o >>= 1) { if (t < o) red[t] += red[t + o]; __syncthreads(); }
    float var = red[0] / D_;
    y[(long)row * D_ + t] = __float2bfloat16(dv * rsqrtf(var + 1e-5f) * g[t] + b[t]);
}

// ---------------- weight transpose+convert: W[K][N] fp32 -> WT[N][K] bf16 ----------------
__global__ __launch_bounds__(256) void conv_w(const float* w0, const float* w1, const float* w2,
                                              const float* w3, const float* w4, const float* w5,
                                              const float* w6, bf16_t* wt) {
    __shared__ float tile[32][33];
    int tb = blockIdx.x;
    const float* W; long dstoff; int K, N, local;
    if (tb < 64)       { W = w0; dstoff = 0;       K = 256;  N = 256;  local = tb; }
    else if (tb < 128) { W = w1; dstoff = 65536;   K = 256;  N = 256;  local = tb - 64; }
    else if (tb < 192) { W = w2; dstoff = 131072;  K = 256;  N = 256;  local = tb - 128; }
    else if (tb < 256) { W = w3; dstoff = 196608;  K = 256;  N = 256;  local = tb - 192; }
    else if (tb < 384) { W = w4; dstoff = 262144;  K = 512;  N = 256;  local = tb - 256; }
    else if (tb < 640) { W = w5; dstoff = 393216;  K = 256;  N = 1024; local = tb - 384; }
    else               { W = w6; dstoff = 655360;  K = 1024; N = 256;  local = tb - 640; }
    int ntn = N >> 5;
    int tk = local / ntn, tn = local - tk * ntn;
    int k0 = tk * 32, n0 = tn * 32;
    int r = threadIdx.x >> 5, c = threadIdx.x & 31;
#pragma unroll
    for (int rr = 0; rr < 4; rr++)
        tile[r + rr * 8][c] = W[(long)(k0 + r + rr * 8) * N + n0 + c];
    __syncthreads();
    bf16_t* dst = wt + dstoff;
#pragma unroll
    for (int rr = 0; rr < 4; rr++)
        dst[(long)(n0 + r + rr * 8) * K + k0 + c] = __float2bfloat16(tile[c][r + rr * 8]);
}

__global__ void conv_bqkv(const float* bq, const float* bk, const float* bv, float* bqkv) {
    int t = threadIdx.x;  // 768
    bqkv[t] = t < 256 ? bq[t] : (t < 512 ? bk[t - 256] : bv[t - 512]);
}

// x fp32 -> bf16 into xcat cols 0..255 (ld 512)
__global__ __launch_bounds__(256) void conv_x(const float* __restrict__ x, bf16_t* __restrict__ xcat) {
    int row = blockIdx.x, t = threadIdx.x;
    xcat[(long)row * 512 + t] = __float2bfloat16(x[(long)row * 256 + t]);
}

// ---------------- MFMA bf16 GEMM, 64x64 tile, BK=64: C = A[M,K] @ WT[N,K]^T ----------------
#define LDT64 72

template<int GELU>
__global__ __launch_bounds__(256) void mgemm64(const bf16_t* __restrict__ A,
                                               const bf16_t* __restrict__ Wt,
                                               const float* __restrict__ bias,
                                               const float* __restrict__ resid,
                                               float* __restrict__ Cf,
                                               bf16_t* __restrict__ Cb,
                                               int M, int N, int K, int ldcb) {
    __shared__ short As[64 * LDT64];
    __shared__ short Bs[64 * LDT64];
    int tid = threadIdx.x;
    int m0 = blockIdx.y * 64, n0 = blockIdx.x * 64;
    int w = tid >> 6, ln = tid & 63;
    int wr = w >> 1, wc = w & 1;
    int srow = tid >> 2, skb = (tid & 3) * 8;
    f32x4 zero4 = {0.f, 0.f, 0.f, 0.f};
    f32x4 acc[2][2];
#pragma unroll
    for (int i = 0; i < 2; i++)
#pragma unroll
        for (int j = 0; j < 2; j++) acc[i][j] = zero4;

    const bf16_t* Ab = A + (long)m0 * K + skb;
    const bf16_t* Bb = Wt + (long)n0 * K + skb;

    for (int k0 = 0; k0 < K; k0 += 64) {
        uint4 a0 = *(const uint4*)(Ab + (long)srow * K + k0);
        uint4 a1 = *(const uint4*)(Ab + (long)srow * K + k0 + 32);
        uint4 b0 = *(const uint4*)(Bb + (long)srow * K + k0);
        uint4 b1 = *(const uint4*)(Bb + (long)srow * K + k0 + 32);
        *(uint4*)(&As[srow * LDT64 + skb]) = a0;
        *(uint4*)(&As[srow * LDT64 + skb + 32]) = a1;
        *(uint4*)(&Bs[srow * LDT64 + skb]) = b0;
        *(uint4*)(&Bs[srow * LDT64 + skb + 32]) = b1;
        __syncthreads();
        int kr = (ln >> 4) * 8;
        int arow = wr * 32 + (ln & 15);
        int brow = wc * 32 + (ln & 15);
        bf16x8 af[2][2], bfr[2][2];
#pragma unroll
        for (int mi = 0; mi < 2; mi++)
#pragma unroll
            for (int ks = 0; ks < 2; ks++)
                af[mi][ks] = *(const bf16x8*)(&As[(arow + mi * 16) * LDT64 + ks * 32 + kr]);
#pragma unroll
        for (int ni = 0; ni < 2; ni++)
#pragma unroll
            for (int ks = 0; ks < 2; ks++)
                bfr[ni][ks] = *(const bf16x8*)(&Bs[(brow + ni * 16) * LDT64 + ks * 32 + kr]);
#pragma unroll
        for (int mi = 0; mi < 2; mi++)
#pragma unroll
            for (int ni = 0; ni < 2; ni++) {
                acc[mi][ni] = __builtin_amdgcn_mfma_f32_16x16x32_bf16(af[mi][0], bfr[ni][0], acc[mi][ni], 0, 0, 0);
                acc[mi][ni] = __builtin_amdgcn_mfma_f32_16x16x32_bf16(af[mi][1], bfr[ni][1], acc[mi][ni], 0, 0, 0);
            }
        __syncthreads();
    }
    // epilogue: D[row=(l>>4)*4+r][col=l&15] per 16x16 frag (m89-verified layout)
    int colb = n0 + wc * 32 + (ln & 15);
    int rowb = m0 + wr * 32 + (ln >> 4) * 4;
#pragma unroll
    for (int ni = 0; ni < 2; ni++) {
        int col = colb + ni * 16;
        float bv = bias ? bias[col] : 0.f;
#pragma unroll
        for (int mi = 0; mi < 2; mi++) {
#pragma unroll
            for (int r = 0; r < 4; r++) {
                int row = rowb + mi * 16 + r;
                float v = acc[mi][ni][r] + bv;
                if (GELU) v = 0.5f * v * (1.0f + erff(v * 0.70710678118654752f));
                if (resid) v += resid[(long)row * N + col];
                if (Cf) Cf[(long)row * N + col] = v;
                if (Cb) Cb[(long)row * ldcb + col] = __float2bfloat16(v);
            }
        }
    }
}

// ---------------- v column sums (v = qkv[:, 512:768]), two-stage ----------------
__global__ void vsum1(const float* __restrict__ qkv, float* __restrict__ part) {
    int b = blockIdx.x >> 6, ch = blockIdx.x & 63;
    int c = threadIdx.x;
    float s = 0.f;
    int j0 = ch * 32;
    for (int j = j0; j < j0 + 32; j++) s += qkv[((long)b * S_ + j) * 768 + 512 + c];
    part[(long)blockIdx.x * QK_ + c] = s;
}

__global__ void vsum2(const float* __restrict__ part, float* __restrict__ vs) {
    int g = blockIdx.x * 256 + threadIdx.x;   // 0..511
    int b = g >> 8, c = g & 255;
    float s = 0.f;
    for (int ch = 0; ch < 64; ch++) s += part[(long)(b * 64 + ch) * QK_ + c];
    vs[g] = s;
}

// ---------------- sparse attention: wave-parallel softmax, exp-once, reg scores ----------------
__global__ __launch_bounds__(256) void attn_kernel(const float* __restrict__ qkv,
                                                   const float* __restrict__ vs,
                                                   const int* __restrict__ ridx,
                                                   const int* __restrict__ nbr_idx,
                                                   const int* __restrict__ nbr_cnt,
                                                   bf16_t* __restrict__ out) {
    __shared__ float qs[QK_];
    __shared__ float ej[H_][MAXN_];
    __shared__ int   nb[MAXN_];
    int bi = blockIdx.x;              // b*S + i
    int b = bi >> 11, i = bi & (S_ - 1);
    int t = threadIdx.x;
    int h = t >> 5, ln = t & 31;
    int r = ridx[i];
    int cnt = nbr_cnt[r];
    qs[t] = qkv[(long)bi * 768 + t];
    for (int p = t; p < cnt; p += 256) nb[p] = nbr_idx[r * MAXN_ + p];
    __syncthreads();
    const float4* qh4 = (const float4*)(qs + h * HD_);
    const float* kvb = qkv + (long)b * S_ * 768;
    float sreg[6];
    float lmax = 0.0f;                // masked zeros always present (cnt << S)
#pragma unroll
    for (int u = 0; u < 6; u++) {
        int p = ln + 32 * u;
        sreg[u] = 0.f;
        if (p < cnt) {
            int j = nb[p];
            const float4* kr4 = (const float4*)(kvb + (long)j * 768 + 256 + h * HD_);
            float s = 0.f;
#pragma unroll
            for (int dd = 0; dd < 8; dd++) {
                float4 k4 = kr4[dd];
                float4 q4 = qh4[dd];
                s = fmaf(q4.x, k4.x, s);
                s = fmaf(q4.y, k4.y, s);
                s = fmaf(q4.z, k4.z, s);
                s = fmaf(q4.w, k4.w, s);
            }
            s *= SCALE_;
            sreg[u] = s;
            lmax = fmaxf(lmax, s);
        }
    }
#pragma unroll
    for (int o = 16; o > 0; o >>= 1) lmax = fmaxf(lmax, __shfl_xor(lmax, o, 32));
    float lz = 0.f;
#pragma unroll
    for (int u = 0; u < 6; u++) {
        int p = ln + 32 * u;
        if (p < cnt) {
            float e = expf(sreg[u] - lmax);
            ej[h][p] = e;
            lz += e;
        }
    }
#pragma unroll
    for (int o = 16; o > 0; o >>= 1) lz += __shfl_xor(lz, o, 32);
    float em = expf(-lmax);
    float Z = lz + (float)(S_ - cnt) * em;
    float accv = 0.f, vn = 0.f;
    const float* vbase = kvb + 512 + h * HD_ + ln;
#pragma unroll 4
    for (int p = 0; p < cnt; p++) {
        int j = nb[p];
        float vv = vbase[(long)j * 768];
        float e = ej[h][p];
        accv = fmaf(e, vv, accv);
        vn += vv;
    }
    float o = (em * (vs[b * QK_ + h * HD_ + ln] - vn) + accv) / Z;
    out[(long)bi * QK_ + h * HD_ + ln] = __float2bfloat16(o);
}

// ---------------- gate + fuse + LN2 (writes fused fp32, h bf16) ----------------
__global__ __launch_bounds__(256) void fuse_ln2_kernel(const float* __restrict__ x,
                                                       const float* __restrict__ ao,
                                                       const float* __restrict__ gp,
                                                       const float* __restrict__ g2,
                                                       const float* __restrict__ b2,
                                                       float* __restrict__ fused,
                                                       bf16_t* __restrict__ h) {
    __shared__ float red[256];
    int row = blockIdx.x, t = threadIdx.x;
    long idx = (long)row * D_ + t;
    float gate = 1.f / (1.f + expf(-gp[idx]));
    float f = gate * x[idx] + (1.f - gate) * ao[idx];
    fused[idx] = f;
    red[t] = f; __syncthreads();
    for (int o = 128; o > 0; o >>= 1) { if (t < o) red[t] += red[t + o]; __syncthreads(); }
    float mean = red[0] / D_;
    __syncthreads();
    float dv = f - mean;
    red[t] = dv * dv; __syncthreads();
    for (int o = 128; o > 0; o >>= 1) { if (t < o) red[t] += red[t + o]; __syncthreads(); }
    float var = red[0] / D_;
    h[idx] = __float2bfloat16(dv * rsqrtf(var + 1e-5f) * g2[t] + b2[t]);
}

extern "C" void kernel_launch(void* const* d_in, const int* in_sizes, int n_in,
                              void* d_out, int out_size, void* d_ws, size_t ws_size,
                              hipStream_t stream) {
    const float* x    = (const float*)d_in[0];
    const int*   ridx = (const int*)d_in[1];
    const void*  adj  = d_in[2];
    const float* rm   = (const float*)d_in[3];
    const float* wq = (const float*)d_in[4],  *bq = (const float*)d_in[5];
    const float* wk = (const float*)d_in[6],  *bk = (const float*)d_in[7];
    const float* wv = (const float*)d_in[8],  *bv = (const float*)d_in[9];
    const float* wo = (const float*)d_in[10], *bo = (const float*)d_in[11];
    const float* ln1g = (const float*)d_in[12], *ln1b = (const float*)d_in[13];
    const float* ln2g = (const float*)d_in[14], *ln2b = (const float*)d_in[15];
    const float* gw  = (const float*)d_in[16], *gb  = (const float*)d_in[17];
    const float* fw1 = (const float*)d_in[18], *fb1 = (const float*)d_in[19];
    const float* fw2 = (const float*)d_in[20], *fb2 = (const float*)d_in[21];
    float* out = (float*)d_out;

    // workspace layout (float units; all offsets 16B-aligned)
    float* wsf      = (float*)d_ws;
    int*   flag     = (int*)d_ws;                  // @0 (64)
    float* nmT      = wsf + 64;                    // 131072
    int*   tk       = (int*)(nmT + 131072);        // 16384
    int*   nbr_idx  = tk + 16384;                  // 393216
    int*   nbr_cnt  = nbr_idx + R_ * MAXN_;        // 2048
    float* qkv      = (float*)(nbr_cnt + 2048);    // 4096*768 = 3145728
    float* vs       = qkv + 3145728;               // 512
    float* gatep    = vs + 512;                    // 1048576
    float* attn_out = gatep + 1048576;             // 1048576
    float* fusedb   = attn_out + 1048576;          // 1048576
    float* part     = fusedb + 1048576;            // 32768
    bf16_t* xn_bf   = (bf16_t*)(part + 32768);     // 1048576 bf16 (524288 fl)
    bf16_t* attnO_bf= (bf16_t*)((float*)xn_bf + 524288);    // 1048576 bf16
    bf16_t* xcat_bf = (bf16_t*)((float*)attnO_bf + 524288); // 4096*512 bf16 (1048576 fl)
    bf16_t* hb_bf   = (bf16_t*)((float*)xcat_bf + 1048576); // 1048576 bf16
    bf16_t* f1_bf   = (bf16_t*)((float*)hb_bf + 524288);    // 4096*1024 bf16 (2097152 fl)
    bf16_t* WT      = (bf16_t*)((float*)f1_bf + 2097152);   // 917504 bf16 (458752 fl)
    float* bqkv     = (float*)WT + 458752;         // 768

    const int MROWS = B_ * S_;                     // 4096

    init_flag<<<1, 1, 0, stream>>>(flag);
    detect_adj<<<256, 256, 0, stream>>>((const unsigned int*)adj, flag);
    norm_rm<<<R_, 64, 0, stream>>>(rm, nmT);
    topk_kernel<<<R_ / 2, 256, 0, stream>>>(nmT, tk);
    build_nbr<<<R_, 256, 0, stream>>>(adj, tk, flag, nbr_idx, nbr_cnt);

    conv_w<<<896, 256, 0, stream>>>(wq, wk, wv, wo, gw, fw1, fw2, WT);
    conv_bqkv<<<1, 768, 0, stream>>>(bq, bk, bv, bqkv);
    conv_x<<<MROWS, 256, 0, stream>>>(x, xcat_bf);

    ln_kernel<<<MROWS, 256, 0, stream>>>(x, ln1g, ln1b, xn_bf);

    // QKV fused: [4096,256] @ [256,768] -> qkv fp32 [4096][768]
    mgemm64<0><<<dim3(768 / 64, MROWS / 64), 256, 0, stream>>>(
        xn_bf, WT + 0, bqkv, nullptr, qkv, nullptr, MROWS, 768, 256, 0);

    vsum1<<<B_ * 64, 256, 0, stream>>>(qkv, part);
    vsum2<<<2, 256, 0, stream>>>(part, vs);
    attn_kernel<<<MROWS, 256, 0, stream>>>(qkv, vs, ridx, nbr_idx, nbr_cnt, attnO_bf);

    // wo: attnO @ wo + bo -> attn_out fp32; bf16 copy into xcat cols 256..511
    mgemm64<0><<<dim3(256 / 64, MROWS / 64), 256, 0, stream>>>(
        attnO_bf, WT + 196608, bo, nullptr, attn_out, xcat_bf + 256, MROWS, 256, 256, 512);

    // gate: [x | attn_out] @ gw + gb -> gatep fp32   (K=512)
    mgemm64<0><<<dim3(256 / 64, MROWS / 64), 256, 0, stream>>>(
        xcat_bf, WT + 262144, gb, nullptr, gatep, nullptr, MROWS, 256, 512, 0);

    fuse_ln2_kernel<<<MROWS, 256, 0, stream>>>(x, attn_out, gatep, ln2g, ln2b, fusedb, hb_bf);

    // FFN1: h @ w1 + b1, gelu -> f1 bf16
    mgemm64<1><<<dim3(1024 / 64, MROWS / 64), 256, 0, stream>>>(
        hb_bf, WT + 393216, fb1, nullptr, nullptr, f1_bf, MROWS, 1024, 256, 1024);

    // FFN2: f1 @ w2 + b2 + fused -> out fp32
    mgemm64<0><<<dim3(256 / 64, MROWS / 64), 256, 0, stream>>>(
        f1_bf, WT + 655360, fb2, fusedb, out, nullptr, MROWS, 256, 1024, 0);
}

// Round 8
// 149.510 us; speedup vs baseline: 5.3146x; 1.1397x over previous
//
#include <hip/hip_runtime.h>
#include <hip/hip_bf16.h>
#include <math.h>

#define B_ 2
#define S_ 2048
#define D_ 256
#define QK_ 256
#define H_ 8
#define HD_ 32
#define MLP_ 1024
#define TOPK_ 8
#define R_ 2048
#define MD_ 64
#define MAXN_ 192

using bf16_t = __hip_bfloat16;
using bf16x8 = __attribute__((ext_vector_type(8))) short;   // 8 bf16 (4 VGPRs)
using f32x4  = __attribute__((ext_vector_type(4))) float;   // 4 fp32 acc

__device__ __constant__ float SCALE_ = 0.17677669529663687f;

// ---------------- adj dtype detection ----------------
__global__ void init_flag(int* flag) { *flag = 0; }

__global__ void detect_adj(const unsigned int* __restrict__ adj, int* __restrict__ flag) {
    long g = (long)blockIdx.x * blockDim.x + threadIdx.x;
    long n = (long)R_ * R_ / 4;
    int found = 0;
    for (long i = g; i < n; i += (long)gridDim.x * blockDim.x) {
        if (adj[i] > 1u) { found = 1; break; }
    }
    if (found) atomicOr(flag, 1);
}

__device__ inline bool adj_on(const void* adj, int isbyte, long idx) {
    if (isbyte) return ((const unsigned char*)adj)[idx] != 0;
    return ((const int*)adj)[idx] != 0;
}

// ---------------- region memory normalize -> bf16 row-major nm_bf[2048][64] ----------------
__global__ void norm_rm(const float* __restrict__ rm, bf16_t* __restrict__ nm_bf) {
    int r = blockIdx.x, t = threadIdx.x;   // 64 threads
    float v = rm[r * MD_ + t];
    float s = v * v;
    for (int o = 32; o > 0; o >>= 1) s += __shfl_down(s, o);
    s = __shfl(s, 0);
    nm_bf[r * MD_ + t] = __float2bfloat16(v / (sqrtf(s) + 1e-8f));
}

// ---------------- top-8 selection from precomputed sim rows: 1 wave/region, 0 barriers ----------------
__global__ __launch_bounds__(256) void topk_sel(const float* __restrict__ sim,
                                                int* __restrict__ tk) {
    int t = threadIdx.x;
    int w = t >> 6, ln = t & 63;
    int r = blockIdx.x * 4 + w;
    const float4* row4 = (const float4*)(sim + (long)r * R_);
    float4 f4[8];
#pragma unroll
    for (int k = 0; k < 8; k++) f4[k] = row4[ln + 64 * k];   // c = 4*(ln+64k)+j
    // diagonal exclusion: c == r
    {
        int rem = (r >> 2) & 63, kw = r >> 8, jw = r & 3;
        if (rem == ln) {
#pragma unroll
            for (int k = 0; k < 8; k++)
                if (k == kw) {
                    if (jw == 0) f4[k].x = -INFINITY;
                    else if (jw == 1) f4[k].y = -INFINITY;
                    else if (jw == 2) f4[k].z = -INFINITY;
                    else f4[k].w = -INFINITY;
                }
        }
    }
    for (int it = 0; it < TOPK_; it++) {
        float bv = -INFINITY; int bi = 0x7fffffff;
#pragma unroll
        for (int k = 0; k < 8; k++) {
            int c0 = 4 * (ln + 64 * k);
            if (f4[k].x > bv) { bv = f4[k].x; bi = c0; }
            if (f4[k].y > bv) { bv = f4[k].y; bi = c0 + 1; }
            if (f4[k].z > bv) { bv = f4[k].z; bi = c0 + 2; }
            if (f4[k].w > bv) { bv = f4[k].w; bi = c0 + 3; }
        }
#pragma unroll
        for (int o = 32; o > 0; o >>= 1) {
            float ov = __shfl_down(bv, o); int oi = __shfl_down(bi, o);
            if (ov > bv || (ov == bv && oi < bi)) { bv = ov; bi = oi; }
        }
        int xi = __shfl(bi, 0);
        if (ln == 0) tk[r * TOPK_ + it] = xi;
        // owner invalidates (static indices)
        int rem = (xi >> 2) & 63, kw = xi >> 8, jw = xi & 3;
        if (rem == ln) {
#pragma unroll
            for (int k = 0; k < 8; k++)
                if (k == kw) {
                    if (jw == 0) f4[k].x = -INFINITY;
                    else if (jw == 1) f4[k].y = -INFINITY;
                    else if (jw == 2) f4[k].z = -INFINITY;
                    else f4[k].w = -INFINITY;
                }
        }
    }
}

// ---------------- neighbor list build (adj union topk) ----------------
__global__ __launch_bounds__(256) void build_nbr(const void* __restrict__ adj,
                                                 const int* __restrict__ tk,
                                                 const int* __restrict__ flag,
                                                 int* __restrict__ nbr_idx,
                                                 int* __restrict__ nbr_cnt) {
    __shared__ int cnt;
    int r = blockIdx.x, t = threadIdx.x;
    if (t == 0) cnt = 0;
    __syncthreads();
    int isbyte = *flag;
    for (int c = t; c < S_; c += 256) {
        long idx = (long)r * R_ + c;
        if (adj_on(adj, isbyte, idx)) {
            int p = atomicAdd(&cnt, 1);
            if (p < MAXN_) nbr_idx[r * MAXN_ + p] = c;
        }
    }
    __syncthreads();
    if (t < TOPK_) {
        int c = tk[r * TOPK_ + t];
        long idx = (long)r * R_ + c;
        if (!adj_on(adj, isbyte, idx) && c < S_) {
            int p = atomicAdd(&cnt, 1);
            if (p < MAXN_) nbr_idx[r * MAXN_ + p] = c;
        }
    }
    __syncthreads();
    if (t == 0) nbr_cnt[r] = min(cnt, MAXN_);
}

// ---------------- layernorm (row of 256) -> bf16 out + xcat bf16 copy of x ----------------
__global__ __launch_bounds__(256) void ln_kernel(const float* __restrict__ x,
                                                 const float* __restrict__ g,
                                                 const float* __restrict__ b,
                                                 bf16_t* __restrict__ y,
                                                 bf16_t* __restrict__ xcat) {
    __shared__ float red[256];
    int row = blockIdx.x, t = threadIdx.x;
    float v = x[(long)row * D_ + t];
    xcat[(long)row * 512 + t] = __float2bfloat16(v);
    red[t] = v; __syncthreads();
    for (int o = 128; o > 0; o >>= 1) { if (t < o) red[t] += red[t + o]; __syncthreads(); }
    float mean = red[0] / D_;
    __syncthreads();
    float dv = v - mean;
    red[t] = dv * dv; __syncthreads();
    for (int o = 128; o > 0; o >>= 1) { if (t < o) red[t] += red[t + o]; __syncthreads(); }
    float var = red[0] / D_;
    y[(long)row * D_ + t] = __float2bfloat16(dv * rsqrtf(var + 1e-5f) * g[t] + b[t]);
}

// ---------------- weight transpose+convert: W[K][N] fp32 -> WT[N][K] bf16 (+bqkv concat) ----------------
__global__ __launch_bounds__(256) void conv_w(const float* w0, const float* w1, const float* w2,
                                              const float* w3, const float* w4, const float* w5,
                                              const float* w6,
                                              const float* bq, const float* bk, const float* bv,
                                              bf16_t* wt, float* bqkv) {
    __shared__ float tile[32][33];
    int tb = blockIdx.x;
    if (tb >= 896) {     // bias concat blocks
        int t = (tb - 896) * 256 + threadIdx.x;   // 0..767
        if (t < 768) bqkv[t] = t < 256 ? bq[t] : (t < 512 ? bk[t - 256] : bv[t - 512]);
        return;
    }
    const float* W; long dstoff; int K, N, local;
    if (tb < 64)       { W = w0; dstoff = 0;       K = 256;  N = 256;  local = tb; }
    else if (tb < 128) { W = w1; dstoff = 65536;   K = 256;  N = 256;  local = tb - 64; }
    else if (tb < 192) { W = w2; dstoff = 131072;  K = 256;  N = 256;  local = tb - 128; }
    else if (tb < 256) { W = w3; dstoff = 196608;  K = 256;  N = 256;  local = tb - 192; }
    else if (tb < 384) { W = w4; dstoff = 262144;  K = 512;  N = 256;  local = tb - 256; }
    else if (tb < 640) { W = w5; dstoff = 393216;  K = 256;  N = 1024; local = tb - 384; }
    else               { W = w6; dstoff = 655360;  K = 1024; N = 256;  local = tb - 640; }
    int ntn = N >> 5;
    int tk = local / ntn, tn = local - tk * ntn;
    int k0 = tk * 32, n0 = tn * 32;
    int r = threadIdx.x >> 5, c = threadIdx.x & 31;
#pragma unroll
    for (int rr = 0; rr < 4; rr++)
        tile[r + rr * 8][c] = W[(long)(k0 + r + rr * 8) * N + n0 + c];
    __syncthreads();
    bf16_t* dst = wt + dstoff;
#pragma unroll
    for (int rr = 0; rr < 4; rr++)
        dst[(long)(n0 + r + rr * 8) * K + k0 + c] = __float2bfloat16(tile[c][r + rr * 8]);
}

// ---------------- MFMA bf16 GEMM, 64x64 tile, BK=64: C = A[M,K] @ WT[N,K]^T ----------------
#define LDT64 72

template<int GELU>
__global__ __launch_bounds__(256) void mgemm64(const bf16_t* __restrict__ A,
                                               const bf16_t* __restrict__ Wt,
                                               const float* __restrict__ bias,
                                               const float* __restrict__ resid,
                                               float* __restrict__ Cf,
                                               bf16_t* __restrict__ Cb,
                                               int M, int N, int K, int ldcb) {
    __shared__ short As[64 * LDT64];
    __shared__ short Bs[64 * LDT64];
    int tid = threadIdx.x;
    int m0 = blockIdx.y * 64, n0 = blockIdx.x * 64;
    int w = tid >> 6, ln = tid & 63;
    int wr = w >> 1, wc = w & 1;
    int srow = tid >> 2, skb = (tid & 3) * 8;
    f32x4 zero4 = {0.f, 0.f, 0.f, 0.f};
    f32x4 acc[2][2];
#pragma unroll
    for (int i = 0; i < 2; i++)
#pragma unroll
        for (int j = 0; j < 2; j++) acc[i][j] = zero4;

    const bf16_t* Ab = A + (long)m0 * K + skb;
    const bf16_t* Bb = Wt + (long)n0 * K + skb;

    for (int k0 = 0; k0 < K; k0 += 64) {
        uint4 a0 = *(const uint4*)(Ab + (long)srow * K + k0);
        uint4 a1 = *(const uint4*)(Ab + (long)srow * K + k0 + 32);
        uint4 b0 = *(const uint4*)(Bb + (long)srow * K + k0);
        uint4 b1 = *(const uint4*)(Bb + (long)srow * K + k0 + 32);
        *(uint4*)(&As[srow * LDT64 + skb]) = a0;
        *(uint4*)(&As[srow * LDT64 + skb + 32]) = a1;
        *(uint4*)(&Bs[srow * LDT64 + skb]) = b0;
        *(uint4*)(&Bs[srow * LDT64 + skb + 32]) = b1;
        __syncthreads();
        int kr = (ln >> 4) * 8;
        int arow = wr * 32 + (ln & 15);
        int brow = wc * 32 + (ln & 15);
        bf16x8 af[2][2], bfr[2][2];
#pragma unroll
        for (int mi = 0; mi < 2; mi++)
#pragma unroll
            for (int ks = 0; ks < 2; ks++)
                af[mi][ks] = *(const bf16x8*)(&As[(arow + mi * 16) * LDT64 + ks * 32 + kr]);
#pragma unroll
        for (int ni = 0; ni < 2; ni++)
#pragma unroll
            for (int ks = 0; ks < 2; ks++)
                bfr[ni][ks] = *(const bf16x8*)(&Bs[(brow + ni * 16) * LDT64 + ks * 32 + kr]);
#pragma unroll
        for (int mi = 0; mi < 2; mi++)
#pragma unroll
            for (int ni = 0; ni < 2; ni++) {
                acc[mi][ni] = __builtin_amdgcn_mfma_f32_16x16x32_bf16(af[mi][0], bfr[ni][0], acc[mi][ni], 0, 0, 0);
                acc[mi][ni] = __builtin_amdgcn_mfma_f32_16x16x32_bf16(af[mi][1], bfr[ni][1], acc[mi][ni], 0, 0, 0);
            }
        __syncthreads();
    }
    // epilogue: D[row=(l>>4)*4+r][col=l&15] per 16x16 frag (m89-verified layout)
    int colb = n0 + wc * 32 + (ln & 15);
    int rowb = m0 + wr * 32 + (ln >> 4) * 4;
#pragma unroll
    for (int ni = 0; ni < 2; ni++) {
        int col = colb + ni * 16;
        float bv = bias ? bias[col] : 0.f;
#pragma unroll
        for (int mi = 0; mi < 2; mi++) {
#pragma unroll
            for (int r = 0; r < 4; r++) {
                int row = rowb + mi * 16 + r;
                float v = acc[mi][ni][r] + bv;
                if (GELU) v = 0.5f * v * (1.0f + erff(v * 0.70710678118654752f));
                if (resid) v += resid[(long)row * N + col];
                if (Cf) Cf[(long)row * N + col] = v;
                if (Cb) Cb[(long)row * ldcb + col] = __float2bfloat16(v);
            }
        }
    }
}

// ---------------- v column sums (v = qkv[:, 512:768]), two-stage ----------------
__global__ void vsum1(const float* __restrict__ qkv, float* __restrict__ part) {
    int b = blockIdx.x >> 6, ch = blockIdx.x & 63;
    int c = threadIdx.x;
    float s = 0.f;
    int j0 = ch * 32;
    for (int j = j0; j < j0 + 32; j++) s += qkv[((long)b * S_ + j) * 768 + 512 + c];
    part[(long)blockIdx.x * QK_ + c] = s;
}

__global__ void vsum2(const float* __restrict__ part, float* __restrict__ vs) {
    int g = blockIdx.x * 256 + threadIdx.x;   // 0..511
    int b = g >> 8, c = g & 255;
    float s = 0.f;
    for (int ch = 0; ch < 64; ch++) s += part[(long)(b * 64 + ch) * QK_ + c];
    vs[g] = s;
}

// ---------------- sparse attention: wave-parallel softmax, exp-once, reg scores ----------------
__global__ __launch_bounds__(256) void attn_kernel(const float* __restrict__ qkv,
                                                   const float* __restrict__ vs,
                                                   const int* __restrict__ ridx,
                                                   const int* __restrict__ nbr_idx,
                                                   const int* __restrict__ nbr_cnt,
                                                   bf16_t* __restrict__ out) {
    __shared__ float qs[QK_];
    __shared__ float ej[H_][MAXN_];
    __shared__ int   nb[MAXN_];
    int bi = blockIdx.x;              // b*S + i
    int b = bi >> 11, i = bi & (S_ - 1);
    int t = threadIdx.x;
    int h = t >> 5, ln = t & 31;
    int r = ridx[i];
    int cnt = nbr_cnt[r];
    qs[t] = qkv[(long)bi * 768 + t];
    for (int p = t; p < cnt; p += 256) nb[p] = nbr_idx[r * MAXN_ + p];
    __syncthreads();
    const float4* qh4 = (const float4*)(qs + h * HD_);
    const float* kvb = qkv + (long)b * S_ * 768;
    float sreg[6];
    float lmax = 0.0f;                // masked zeros always present (cnt << S)
#pragma unroll
    for (int u = 0; u < 6; u++) {
        int p = ln + 32 * u;
        sreg[u] = 0.f;
        if (p < cnt) {
            int j = nb[p];
            const float4* kr4 = (const float4*)(kvb + (long)j * 768 + 256 + h * HD_);
            float s = 0.f;
#pragma unroll
            for (int dd = 0; dd < 8; dd++) {
                float4 k4 = kr4[dd];
                float4 q4 = qh4[dd];
                s = fmaf(q4.x, k4.x, s);
                s = fmaf(q4.y, k4.y, s);
                s = fmaf(q4.z, k4.z, s);
                s = fmaf(q4.w, k4.w, s);
            }
            s *= SCALE_;
            sreg[u] = s;
            lmax = fmaxf(lmax, s);
        }
    }
#pragma unroll
    for (int o = 16; o > 0; o >>= 1) lmax = fmaxf(lmax, __shfl_xor(lmax, o, 32));
    float lz = 0.f;
#pragma unroll
    for (int u = 0; u < 6; u++) {
        int p = ln + 32 * u;
        if (p < cnt) {
            float e = expf(sreg[u] - lmax);
            ej[h][p] = e;
            lz += e;
        }
    }
#pragma unroll
    for (int o = 16; o > 0; o >>= 1) lz += __shfl_xor(lz, o, 32);
    float em = expf(-lmax);
    float Z = lz + (float)(S_ - cnt) * em;
    float accv = 0.f, vn = 0.f;
    const float* vbase = kvb + 512 + h * HD_ + ln;
#pragma unroll 4
    for (int p = 0; p < cnt; p++) {
        int j = nb[p];
        float vv = vbase[(long)j * 768];
        float e = ej[h][p];
        accv = fmaf(e, vv, accv);
        vn += vv;
    }
    float o = (em * (vs[b * QK_ + h * HD_ + ln] - vn) + accv) / Z;
    out[(long)bi * QK_ + h * HD_ + ln] = __float2bfloat16(o);
}

// ---------------- gate + fuse + LN2 (writes fused fp32, h bf16) ----------------
__global__ __launch_bounds__(256) void fuse_ln2_kernel(const float* __restrict__ x,
                                                       const float* __restrict__ ao,
                                                       const float* __restrict__ gp,
                                                       const float* __restrict__ g2,
                                                       const float* __restrict__ b2,
                                                       float* __restrict__ fused,
                                                       bf16_t* __restrict__ h) {
    __shared__ float red[256];
    int row = blockIdx.x, t = threadIdx.x;
    long idx = (long)row * D_ + t;
    float gate = 1.f / (1.f + expf(-gp[idx]));
    float f = gate * x[idx] + (1.f - gate) * ao[idx];
    fused[idx] = f;
    red[t] = f; __syncthreads();
    for (int o = 128; o > 0; o >>= 1) { if (t < o) red[t] += red[t + o]; __syncthreads(); }
    float mean = red[0] / D_;
    __syncthreads();
    float dv = f - mean;
    red[t] = dv * dv; __syncthreads();
    for (int o = 128; o > 0; o >>= 1) { if (t < o) red[t] += red[t + o]; __syncthreads(); }
    float var = red[0] / D_;
    h[idx] = __float2bfloat16(dv * rsqrtf(var + 1e-5f) * g2[t] + b2[t]);
}

extern "C" void kernel_launch(void* const* d_in, const int* in_sizes, int n_in,
                              void* d_out, int out_size, void* d_ws, size_t ws_size,
                              hipStream_t stream) {
    const float* x    = (const float*)d_in[0];
    const int*   ridx = (const int*)d_in[1];
    const void*  adj  = d_in[2];
    const float* rm   = (const float*)d_in[3];
    const float* wq = (const float*)d_in[4],  *bq = (const float*)d_in[5];
    const float* wk = (const float*)d_in[6],  *bk = (const float*)d_in[7];
    const float* wv = (const float*)d_in[8],  *bv = (const float*)d_in[9];
    const float* wo = (const float*)d_in[10], *bo = (const float*)d_in[11];
    const float* ln1g = (const float*)d_in[12], *ln1b = (const float*)d_in[13];
    const float* ln2g = (const float*)d_in[14], *ln2b = (const float*)d_in[15];
    const float* gw  = (const float*)d_in[16], *gb  = (const float*)d_in[17];
    const float* fw1 = (const float*)d_in[18], *fb1 = (const float*)d_in[19];
    const float* fw2 = (const float*)d_in[20], *fb2 = (const float*)d_in[21];
    float* out = (float*)d_out;

    // workspace layout (float units; all offsets 16B-aligned)
    float* wsf      = (float*)d_ws;
    int*   flag     = (int*)d_ws;                  // @0 (64)
    bf16_t* nm_bf   = (bf16_t*)(wsf + 64);         // 2048*64 bf16 (65536 fl) in old nmT slot (131072)
    int*   tk       = (int*)(wsf + 64 + 131072);   // 16384
    int*   nbr_idx  = tk + 16384;                  // 393216
    int*   nbr_cnt  = nbr_idx + R_ * MAXN_;        // 2048
    float* qkv      = (float*)(nbr_cnt + 2048);    // 4096*768 = 3145728
    float* vs       = qkv + 3145728;               // 512
    float* gatep    = vs + 512;                    // 1048576
    float* attn_out = gatep + 1048576;             // 1048576
    float* fusedb   = attn_out + 1048576;          // 1048576
    float* part     = fusedb + 1048576;            // 32768
    bf16_t* xn_bf   = (bf16_t*)(part + 32768);     // 1048576 bf16 (524288 fl)
    bf16_t* attnO_bf= (bf16_t*)((float*)xn_bf + 524288);    // 1048576 bf16
    bf16_t* xcat_bf = (bf16_t*)((float*)attnO_bf + 524288); // 4096*512 bf16 (1048576 fl)
    bf16_t* hb_bf   = (bf16_t*)((float*)xcat_bf + 1048576); // 1048576 bf16
    bf16_t* f1_bf   = (bf16_t*)((float*)hb_bf + 524288);    // 4096*1024 bf16 (2097152 fl)
    bf16_t* WT      = (bf16_t*)((float*)f1_bf + 2097152);   // 917504 bf16 (458752 fl)
    float* bqkv     = (float*)WT + 458752;         // 768
    float* sim      = bqkv + 768;                  // R*R = 4194304 (16 MB)

    const int MROWS = B_ * S_;                     // 4096

    init_flag<<<1, 1, 0, stream>>>(flag);
    detect_adj<<<256, 256, 0, stream>>>((const unsigned int*)adj, flag);
    norm_rm<<<R_, 64, 0, stream>>>(rm, nm_bf);

    // sim = nm @ nm^T via MFMA (M=N=2048, K=64), then 0-barrier top-8 selection
    mgemm64<0><<<dim3(R_ / 64, R_ / 64), 256, 0, stream>>>(
        nm_bf, nm_bf, nullptr, nullptr, sim, nullptr, R_, R_, MD_, 0);
    topk_sel<<<R_ / 4, 256, 0, stream>>>(sim, tk);

    build_nbr<<<R_, 256, 0, stream>>>(adj, tk, flag, nbr_idx, nbr_cnt);

    conv_w<<<899, 256, 0, stream>>>(wq, wk, wv, wo, gw, fw1, fw2, bq, bk, bv, WT, bqkv);

    ln_kernel<<<MROWS, 256, 0, stream>>>(x, ln1g, ln1b, xn_bf, xcat_bf);

    // QKV fused: [4096,256] @ [256,768] -> qkv fp32 [4096][768]
    mgemm64<0><<<dim3(768 / 64, MROWS / 64), 256, 0, stream>>>(
        xn_bf, WT + 0, bqkv, nullptr, qkv, nullptr, MROWS, 768, 256, 0);

    vsum1<<<B_ * 64, 256, 0, stream>>>(qkv, part);
    vsum2<<<2, 256, 0, stream>>>(part, vs);
    attn_kernel<<<MROWS, 256, 0, stream>>>(qkv, vs, ridx, nbr_idx, nbr_cnt, attnO_bf);

    // wo: attnO @ wo + bo -> attn_out fp32; bf16 copy into xcat cols 256..511
    mgemm64<0><<<dim3(256 / 64, MROWS / 64), 256, 0, stream>>>(
        attnO_bf, WT + 196608, bo, nullptr, attn_out, xcat_bf + 256, MROWS, 256, 256, 512);

    // gate: [x | attn_out] @ gw + gb -> gatep fp32   (K=512)
    mgemm64<0><<<dim3(256 / 64, MROWS / 64), 256, 0, stream>>>(
        xcat_bf, WT + 262144, gb, nullptr, gatep, nullptr, MROWS, 256, 512, 0);

    fuse_ln2_kernel<<<MROWS, 256, 0, stream>>>(x, attn_out, gatep, ln2g, ln2b, fusedb, hb_bf);

    // FFN1: h @ w1 + b1, gelu -> f1 bf16
    mgemm64<1><<<dim3(1024 / 64, MROWS / 64), 256, 0, stream>>>(
        hb_bf, WT + 393216, fb1, nullptr, nullptr, f1_bf, MROWS, 1024, 256, 1024);

    // FFN2: f1 @ w2 + b2 + fused -> out fp32
    mgemm64<0><<<dim3(256 / 64, MROWS / 64), 256, 0, stream>>>(
        f1_bf, WT + 655360, fb2, fusedb, out, nullptr, MROWS, 256, 1024, 0);
}

// Round 9
// 136.513 us; speedup vs baseline: 5.8206x; 1.0952x over previous
//
#include <hip/hip_runtime.h>
#include <hip/hip_bf16.h>
#include <math.h>

#define B_ 2
#define S_ 2048
#define D_ 256
#define QK_ 256
#define H_ 8
#define HD_ 32
#define MLP_ 1024
#define TOPK_ 8
#define R_ 2048
#define MD_ 64
#define MAXN_ 192

using bf16_t = __hip_bfloat16;
using bf16x8 = __attribute__((ext_vector_type(8))) short;   // 8 bf16 (4 VGPRs)
using f32x4  = __attribute__((ext_vector_type(4))) float;   // 4 fp32 acc

__device__ __constant__ float SCALE_ = 0.17677669529663687f;

__device__ inline float bf2f(short s) {
    union { unsigned int u; float f; } cvt;
    cvt.u = ((unsigned int)(unsigned short)s) << 16;
    return cvt.f;
}

// ---------------- adj dtype detection ----------------
__global__ void detect_adj(const unsigned int* __restrict__ adj, int* __restrict__ flag) {
    long g = (long)blockIdx.x * blockDim.x + threadIdx.x;
    long n = (long)R_ * R_ / 4;
    int found = 0;
    for (long i = g; i < n; i += (long)gridDim.x * blockDim.x) {
        if (adj[i] > 1u) { found = 1; break; }
    }
    if (found) atomicOr(flag, 1);
}

__device__ inline bool adj_on(const void* adj, int isbyte, long idx) {
    if (isbyte) return ((const unsigned char*)adj)[idx] != 0;
    return ((const int*)adj)[idx] != 0;
}

// ---------------- region memory normalize -> bf16 row-major nm_bf[2048][64]; also inits flag ----------------
__global__ void norm_rm(const float* __restrict__ rm, bf16_t* __restrict__ nm_bf,
                        int* __restrict__ flag) {
    int r = blockIdx.x, t = threadIdx.x;   // 64 threads
    if (r == 0 && t == 0) *flag = 0;       // runs before detect_adj (stream order)
    float v = rm[r * MD_ + t];
    float s = v * v;
    for (int o = 32; o > 0; o >>= 1) s += __shfl_down(s, o);
    s = __shfl(s, 0);
    nm_bf[r * MD_ + t] = __float2bfloat16(v / (sqrtf(s) + 1e-8f));
}

// ---------------- top-8 selection from precomputed sim rows: 1 wave/region, 0 barriers ----------------
__global__ __launch_bounds__(256) void topk_sel(const float* __restrict__ sim,
                                                int* __restrict__ tk) {
    int t = threadIdx.x;
    int w = t >> 6, ln = t & 63;
    int r = blockIdx.x * 4 + w;
    const float4* row4 = (const float4*)(sim + (long)r * R_);
    float4 f4[8];
#pragma unroll
    for (int k = 0; k < 8; k++) f4[k] = row4[ln + 64 * k];   // c = 4*(ln+64k)+j
    // diagonal exclusion: c == r
    {
        int rem = (r >> 2) & 63, kw = r >> 8, jw = r & 3;
        if (rem == ln) {
#pragma unroll
            for (int k = 0; k < 8; k++)
                if (k == kw) {
                    if (jw == 0) f4[k].x = -INFINITY;
                    else if (jw == 1) f4[k].y = -INFINITY;
                    else if (jw == 2) f4[k].z = -INFINITY;
                    else f4[k].w = -INFINITY;
                }
        }
    }
    for (int it = 0; it < TOPK_; it++) {
        float bv = -INFINITY; int bi = 0x7fffffff;
#pragma unroll
        for (int k = 0; k < 8; k++) {
            int c0 = 4 * (ln + 64 * k);
            if (f4[k].x > bv) { bv = f4[k].x; bi = c0; }
            if (f4[k].y > bv) { bv = f4[k].y; bi = c0 + 1; }
            if (f4[k].z > bv) { bv = f4[k].z; bi = c0 + 2; }
            if (f4[k].w > bv) { bv = f4[k].w; bi = c0 + 3; }
        }
#pragma unroll
        for (int o = 32; o > 0; o >>= 1) {
            float ov = __shfl_down(bv, o); int oi = __shfl_down(bi, o);
            if (ov > bv || (ov == bv && oi < bi)) { bv = ov; bi = oi; }
        }
        int xi = __shfl(bi, 0);
        if (ln == 0) tk[r * TOPK_ + it] = xi;
        // owner invalidates (static indices)
        int rem = (xi >> 2) & 63, kw = xi >> 8, jw = xi & 3;
        if (rem == ln) {
#pragma unroll
            for (int k = 0; k < 8; k++)
                if (k == kw) {
                    if (jw == 0) f4[k].x = -INFINITY;
                    else if (jw == 1) f4[k].y = -INFINITY;
                    else if (jw == 2) f4[k].z = -INFINITY;
                    else f4[k].w = -INFINITY;
                }
        }
    }
}

// ---------------- neighbor list build (adj union topk) ----------------
__global__ __launch_bounds__(256) void build_nbr(const void* __restrict__ adj,
                                                 const int* __restrict__ tk,
                                                 const int* __restrict__ flag,
                                                 int* __restrict__ nbr_idx,
                                                 int* __restrict__ nbr_cnt) {
    __shared__ int cnt;
    int r = blockIdx.x, t = threadIdx.x;
    if (t == 0) cnt = 0;
    __syncthreads();
    int isbyte = *flag;
    for (int c = t; c < S_; c += 256) {
        long idx = (long)r * R_ + c;
        if (adj_on(adj, isbyte, idx)) {
            int p = atomicAdd(&cnt, 1);
            if (p < MAXN_) nbr_idx[r * MAXN_ + p] = c;
        }
    }
    __syncthreads();
    if (t < TOPK_) {
        int c = tk[r * TOPK_ + t];
        long idx = (long)r * R_ + c;
        if (!adj_on(adj, isbyte, idx) && c < S_) {
            int p = atomicAdd(&cnt, 1);
            if (p < MAXN_) nbr_idx[r * MAXN_ + p] = c;
        }
    }
    __syncthreads();
    if (t == 0) nbr_cnt[r] = min(cnt, MAXN_);
}

// ---------------- layernorm (row of 256) -> bf16 out + xcat bf16 copy of x ----------------
__global__ __launch_bounds__(256) void ln_kernel(const float* __restrict__ x,
                                                 const float* __restrict__ g,
                                                 const float* __restrict__ b,
                                                 bf16_t* __restrict__ y,
                                                 bf16_t* __restrict__ xcat) {
    __shared__ float red[256];
    int row = blockIdx.x, t = threadIdx.x;
    float v = x[(long)row * D_ + t];
    xcat[(long)row * 512 + t] = __float2bfloat16(v);
    red[t] = v; __syncthreads();
    for (int o = 128; o > 0; o >>= 1) { if (t < o) red[t] += red[t + o]; __syncthreads(); }
    float mean = red[0] / D_;
    __syncthreads();
    float dv = v - mean;
    red[t] = dv * dv; __syncthreads();
    for (int o = 128; o > 0; o >>= 1) { if (t < o) red[t] += red[t + o]; __syncthreads(); }
    float var = red[0] / D_;
    y[(long)row * D_ + t] = __float2bfloat16(dv * rsqrtf(var + 1e-5f) * g[t] + b[t]);
}

// ---------------- weight transpose+convert: W[K][N] fp32 -> WT[N][K] bf16 (+bqkv concat) ----------------
__global__ __launch_bounds__(256) void conv_w(const float* w0, const float* w1, const float* w2,
                                              const float* w3, const float* w4, const float* w5,
                                              const float* w6,
                                              const float* bq, const float* bk, const float* bv,
                                              bf16_t* wt, float* bqkv) {
    __shared__ float tile[32][33];
    int tb = blockIdx.x;
    if (tb >= 896) {     // bias concat blocks
        int t = (tb - 896) * 256 + threadIdx.x;   // 0..767
        if (t < 768) bqkv[t] = t < 256 ? bq[t] : (t < 512 ? bk[t - 256] : bv[t - 512]);
        return;
    }
    const float* W; long dstoff; int K, N, local;
    if (tb < 64)       { W = w0; dstoff = 0;       K = 256;  N = 256;  local = tb; }
    else if (tb < 128) { W = w1; dstoff = 65536;   K = 256;  N = 256;  local = tb - 64; }
    else if (tb < 192) { W = w2; dstoff = 131072;  K = 256;  N = 256;  local = tb - 128; }
    else if (tb < 256) { W = w3; dstoff = 196608;  K = 256;  N = 256;  local = tb - 192; }
    else if (tb < 384) { W = w4; dstoff = 262144;  K = 512;  N = 256;  local = tb - 256; }
    else if (tb < 640) { W = w5; dstoff = 393216;  K = 256;  N = 1024; local = tb - 384; }
    else               { W = w6; dstoff = 655360;  K = 1024; N = 256;  local = tb - 640; }
    int ntn = N >> 5;
    int tk = local / ntn, tn = local - tk * ntn;
    int k0 = tk * 32, n0 = tn * 32;
    int r = threadIdx.x >> 5, c = threadIdx.x & 31;
#pragma unroll
    for (int rr = 0; rr < 4; rr++)
        tile[r + rr * 8][c] = W[(long)(k0 + r + rr * 8) * N + n0 + c];
    __syncthreads();
    bf16_t* dst = wt + dstoff;
#pragma unroll
    for (int rr = 0; rr < 4; rr++)
        dst[(long)(n0 + r + rr * 8) * K + k0 + c] = __float2bfloat16(tile[c][r + rr * 8]);
}

// ---------------- MFMA bf16 GEMM, 64x64 tile, BK=64: C = A[M,K] @ WT[N,K]^T ----------------
#define LDT64 72

template<int GELU>
__global__ __launch_bounds__(256) void mgemm64(const bf16_t* __restrict__ A,
                                               const bf16_t* __restrict__ Wt,
                                               const float* __restrict__ bias,
                                               const float* __restrict__ resid,
                                               float* __restrict__ Cf,
                                               bf16_t* __restrict__ Cb,
                                               int M, int N, int K, int ldcb) {
    __shared__ short As[64 * LDT64];
    __shared__ short Bs[64 * LDT64];
    int tid = threadIdx.x;
    int m0 = blockIdx.y * 64, n0 = blockIdx.x * 64;
    int w = tid >> 6, ln = tid & 63;
    int wr = w >> 1, wc = w & 1;
    int srow = tid >> 2, skb = (tid & 3) * 8;
    f32x4 zero4 = {0.f, 0.f, 0.f, 0.f};
    f32x4 acc[2][2];
#pragma unroll
    for (int i = 0; i < 2; i++)
#pragma unroll
        for (int j = 0; j < 2; j++) acc[i][j] = zero4;

    const bf16_t* Ab = A + (long)m0 * K + skb;
    const bf16_t* Bb = Wt + (long)n0 * K + skb;

    for (int k0 = 0; k0 < K; k0 += 64) {
        uint4 a0 = *(const uint4*)(Ab + (long)srow * K + k0);
        uint4 a1 = *(const uint4*)(Ab + (long)srow * K + k0 + 32);
        uint4 b0 = *(const uint4*)(Bb + (long)srow * K + k0);
        uint4 b1 = *(const uint4*)(Bb + (long)srow * K + k0 + 32);
        *(uint4*)(&As[srow * LDT64 + skb]) = a0;
        *(uint4*)(&As[srow * LDT64 + skb + 32]) = a1;
        *(uint4*)(&Bs[srow * LDT64 + skb]) = b0;
        *(uint4*)(&Bs[srow * LDT64 + skb + 32]) = b1;
        __syncthreads();
        int kr = (ln >> 4) * 8;
        int arow = wr * 32 + (ln & 15);
        int brow = wc * 32 + (ln & 15);
        bf16x8 af[2][2], bfr[2][2];
#pragma unroll
        for (int mi = 0; mi < 2; mi++)
#pragma unroll
            for (int ks = 0; ks < 2; ks++)
                af[mi][ks] = *(const bf16x8*)(&As[(arow + mi * 16) * LDT64 + ks * 32 + kr]);
#pragma unroll
        for (int ni = 0; ni < 2; ni++)
#pragma unroll
            for (int ks = 0; ks < 2; ks++)
                bfr[ni][ks] = *(const bf16x8*)(&Bs[(brow + ni * 16) * LDT64 + ks * 32 + kr]);
#pragma unroll
        for (int mi = 0; mi < 2; mi++)
#pragma unroll
            for (int ni = 0; ni < 2; ni++) {
                acc[mi][ni] = __builtin_amdgcn_mfma_f32_16x16x32_bf16(af[mi][0], bfr[ni][0], acc[mi][ni], 0, 0, 0);
                acc[mi][ni] = __builtin_amdgcn_mfma_f32_16x16x32_bf16(af[mi][1], bfr[ni][1], acc[mi][ni], 0, 0, 0);
            }
        __syncthreads();
    }
    // epilogue: D[row=(l>>4)*4+r][col=l&15] per 16x16 frag (m89-verified layout)
    int colb = n0 + wc * 32 + (ln & 15);
    int rowb = m0 + wr * 32 + (ln >> 4) * 4;
#pragma unroll
    for (int ni = 0; ni < 2; ni++) {
        int col = colb + ni * 16;
        float bv = bias ? bias[col] : 0.f;
#pragma unroll
        for (int mi = 0; mi < 2; mi++) {
#pragma unroll
            for (int r = 0; r < 4; r++) {
                int row = rowb + mi * 16 + r;
                float v = acc[mi][ni][r] + bv;
                if (GELU) v = 0.5f * v * (1.0f + erff(v * 0.70710678118654752f));
                if (resid) v += resid[(long)row * N + col];
                if (Cf) Cf[(long)row * N + col] = v;
                if (Cb) Cb[(long)row * ldcb + col] = __float2bfloat16(v);
            }
        }
    }
}

// ---------------- v column sums (v = qkv_bf[:, 512:768]), two-stage ----------------
__global__ void vsum1(const bf16_t* __restrict__ qkv, float* __restrict__ part) {
    int b = blockIdx.x >> 6, ch = blockIdx.x & 63;
    int c = threadIdx.x;
    float s = 0.f;
    int j0 = ch * 32;
    for (int j = j0; j < j0 + 32; j++)
        s += __bfloat162float(qkv[((long)b * S_ + j) * 768 + 512 + c]);
    part[(long)blockIdx.x * QK_ + c] = s;
}

__global__ void vsum2(const float* __restrict__ part, float* __restrict__ vs) {
    int g = blockIdx.x * 256 + threadIdx.x;   // 0..511
    int b = g >> 8, c = g & 255;
    float s = 0.f;
    for (int ch = 0; ch < 64; ch++) s += part[(long)(b * 64 + ch) * QK_ + c];
    vs[g] = s;
}

// ---------------- sparse attention: bf16 K/V gathers, wave-parallel softmax ----------------
__global__ __launch_bounds__(256) void attn_kernel(const bf16_t* __restrict__ qkv,
                                                   const float* __restrict__ vs,
                                                   const int* __restrict__ ridx,
                                                   const int* __restrict__ nbr_idx,
                                                   const int* __restrict__ nbr_cnt,
                                                   bf16_t* __restrict__ out) {
    __shared__ float qs[QK_];
    __shared__ float ej[H_][MAXN_];
    __shared__ int   nb[MAXN_];
    int bi = blockIdx.x;              // b*S + i
    int b = bi >> 11, i = bi & (S_ - 1);
    int t = threadIdx.x;
    int h = t >> 5, ln = t & 31;
    int r = ridx[i];
    int cnt = nbr_cnt[r];
    qs[t] = __bfloat162float(qkv[(long)bi * 768 + t]);
    for (int p = t; p < cnt; p += 256) nb[p] = nbr_idx[r * MAXN_ + p];
    __syncthreads();
    const float* qh = qs + h * HD_;
    const bf16_t* kvb = qkv + (long)b * S_ * 768;
    float sreg[6];
    float lmax = 0.0f;                // masked zeros always present (cnt << S)
#pragma unroll
    for (int u = 0; u < 6; u++) {
        int p = ln + 32 * u;
        sreg[u] = 0.f;
        if (p < cnt) {
            int j = nb[p];
            const bf16x8* kr8 = (const bf16x8*)(kvb + (long)j * 768 + 256 + h * HD_);
            float s = 0.f;
#pragma unroll
            for (int q8 = 0; q8 < 4; q8++) {
                bf16x8 kk = kr8[q8];
#pragma unroll
                for (int e = 0; e < 8; e++)
                    s = fmaf(qh[q8 * 8 + e], bf2f(kk[e]), s);
            }
            s *= SCALE_;
            sreg[u] = s;
            lmax = fmaxf(lmax, s);
        }
    }
#pragma unroll
    for (int o = 16; o > 0; o >>= 1) lmax = fmaxf(lmax, __shfl_xor(lmax, o, 32));
    float lz = 0.f;
#pragma unroll
    for (int u = 0; u < 6; u++) {
        int p = ln + 32 * u;
        if (p < cnt) {
            float e = expf(sreg[u] - lmax);
            ej[h][p] = e;
            lz += e;
        }
    }
#pragma unroll
    for (int o = 16; o > 0; o >>= 1) lz += __shfl_xor(lz, o, 32);
    float em = expf(-lmax);
    float Z = lz + (float)(S_ - cnt) * em;
    float accv = 0.f, vn = 0.f;
    const bf16_t* vbase = kvb + 512 + h * HD_ + ln;
#pragma unroll 8
    for (int p = 0; p < cnt; p++) {
        int j = nb[p];
        float vv = __bfloat162float(vbase[(long)j * 768]);
        float e = ej[h][p];
        accv = fmaf(e, vv, accv);
        vn += vv;
    }
    float o = (em * (vs[b * QK_ + h * HD_ + ln] - vn) + accv) / Z;
    out[(long)bi * QK_ + h * HD_ + ln] = __float2bfloat16(o);
}

// ---------------- gate + fuse + LN2 (writes fused fp32, h bf16) ----------------
__global__ __launch_bounds__(256) void fuse_ln2_kernel(const float* __restrict__ x,
                                                       const float* __restrict__ ao,
                                                       const float* __restrict__ gp,
                                                       const float* __restrict__ g2,
                                                       const float* __restrict__ b2,
                                                       float* __restrict__ fused,
                                                       bf16_t* __restrict__ h) {
    __shared__ float red[256];
    int row = blockIdx.x, t = threadIdx.x;
    long idx = (long)row * D_ + t;
    float gate = 1.f / (1.f + expf(-gp[idx]));
    float f = gate * x[idx] + (1.f - gate) * ao[idx];
    fused[idx] = f;
    red[t] = f; __syncthreads();
    for (int o = 128; o > 0; o >>= 1) { if (t < o) red[t] += red[t + o]; __syncthreads(); }
    float mean = red[0] / D_;
    __syncthreads();
    float dv = f - mean;
    red[t] = dv * dv; __syncthreads();
    for (int o = 128; o > 0; o >>= 1) { if (t < o) red[t] += red[t + o]; __syncthreads(); }
    float var = red[0] / D_;
    h[idx] = __float2bfloat16(dv * rsqrtf(var + 1e-5f) * g2[t] + b2[t]);
}

extern "C" void kernel_launch(void* const* d_in, const int* in_sizes, int n_in,
                              void* d_out, int out_size, void* d_ws, size_t ws_size,
                              hipStream_t stream) {
    const float* x    = (const float*)d_in[0];
    const int*   ridx = (const int*)d_in[1];
    const void*  adj  = d_in[2];
    const float* rm   = (const float*)d_in[3];
    const float* wq = (const float*)d_in[4],  *bq = (const float*)d_in[5];
    const float* wk = (const float*)d_in[6],  *bk = (const float*)d_in[7];
    const float* wv = (const float*)d_in[8],  *bv = (const float*)d_in[9];
    const float* wo = (const float*)d_in[10], *bo = (const float*)d_in[11];
    const float* ln1g = (const float*)d_in[12], *ln1b = (const float*)d_in[13];
    const float* ln2g = (const float*)d_in[14], *ln2b = (const float*)d_in[15];
    const float* gw  = (const float*)d_in[16], *gb  = (const float*)d_in[17];
    const float* fw1 = (const float*)d_in[18], *fb1 = (const float*)d_in[19];
    const float* fw2 = (const float*)d_in[20], *fb2 = (const float*)d_in[21];
    float* out = (float*)d_out;

    // workspace layout (float units; all offsets 16B-aligned)
    float* wsf      = (float*)d_ws;
    int*   flag     = (int*)d_ws;                  // @0 (64)
    bf16_t* nm_bf   = (bf16_t*)(wsf + 64);         // 2048*64 bf16 in 131072-fl slot
    int*   tk       = (int*)(wsf + 64 + 131072);   // 16384
    int*   nbr_idx  = tk + 16384;                  // 393216
    int*   nbr_cnt  = nbr_idx + R_ * MAXN_;        // 2048
    bf16_t* qkv_bf  = (bf16_t*)(nbr_cnt + 2048);   // 4096*768 bf16 (in 3145728-fl slot)
    float* vs       = (float*)(nbr_cnt + 2048) + 3145728;  // 512
    float* gatep    = vs + 512;                    // 1048576
    float* attn_out = gatep + 1048576;             // 1048576
    float* fusedb   = attn_out + 1048576;          // 1048576
    float* part     = fusedb + 1048576;            // 32768
    bf16_t* xn_bf   = (bf16_t*)(part + 32768);     // 1048576 bf16 (524288 fl)
    bf16_t* attnO_bf= (bf16_t*)((float*)xn_bf + 524288);    // 1048576 bf16
    bf16_t* xcat_bf = (bf16_t*)((float*)attnO_bf + 524288); // 4096*512 bf16 (1048576 fl)
    bf16_t* hb_bf   = (bf16_t*)((float*)xcat_bf + 1048576); // 1048576 bf16
    bf16_t* f1_bf   = (bf16_t*)((float*)hb_bf + 524288);    // 4096*1024 bf16 (2097152 fl)
    bf16_t* WT      = (bf16_t*)((float*)f1_bf + 2097152);   // 917504 bf16 (458752 fl)
    float* bqkv     = (float*)WT + 458752;         // 768
    float* sim      = bqkv + 768;                  // R*R = 4194304 (16 MB)

    const int MROWS = B_ * S_;                     // 4096

    norm_rm<<<R_, 64, 0, stream>>>(rm, nm_bf, flag);        // also inits flag=0
    detect_adj<<<256, 256, 0, stream>>>((const unsigned int*)adj, flag);

    // sim = nm @ nm^T via MFMA (M=N=2048, K=64), then 0-barrier top-8 selection
    mgemm64<0><<<dim3(R_ / 64, R_ / 64), 256, 0, stream>>>(
        nm_bf, nm_bf, nullptr, nullptr, sim, nullptr, R_, R_, MD_, 0);
    topk_sel<<<R_ / 4, 256, 0, stream>>>(sim, tk);

    build_nbr<<<R_, 256, 0, stream>>>(adj, tk, flag, nbr_idx, nbr_cnt);

    conv_w<<<899, 256, 0, stream>>>(wq, wk, wv, wo, gw, fw1, fw2, bq, bk, bv, WT, bqkv);

    ln_kernel<<<MROWS, 256, 0, stream>>>(x, ln1g, ln1b, xn_bf, xcat_bf);

    // QKV fused: [4096,256] @ [256,768] -> qkv bf16 [4096][768]
    mgemm64<0><<<dim3(768 / 64, MROWS / 64), 256, 0, stream>>>(
        xn_bf, WT + 0, bqkv, nullptr, nullptr, qkv_bf, MROWS, 768, 256, 768);

    vsum1<<<B_ * 64, 256, 0, stream>>>(qkv_bf, part);
    vsum2<<<2, 256, 0, stream>>>(part, vs);
    attn_kernel<<<MROWS, 256, 0, stream>>>(qkv_bf, vs, ridx, nbr_idx, nbr_cnt, attnO_bf);

    // wo: attnO @ wo + bo -> attn_out fp32; bf16 copy into xcat cols 256..511
    mgemm64<0><<<dim3(256 / 64, MROWS / 64), 256, 0, stream>>>(
        attnO_bf, WT + 196608, bo, nullptr, attn_out, xcat_bf + 256, MROWS, 256, 256, 512);

    // gate: [x | attn_out] @ gw + gb -> gatep fp32   (K=512)
    mgemm64<0><<<dim3(256 / 64, MROWS / 64), 256, 0, stream>>>(
        xcat_bf, WT + 262144, gb, nullptr, gatep, nullptr, MROWS, 256, 512, 0);

    fuse_ln2_kernel<<<MROWS, 256, 0, stream>>>(x, attn_out, gatep, ln2g, ln2b, fusedb, hb_bf);

    // FFN1: h @ w1 + b1, gelu -> f1 bf16
    mgemm64<1><<<dim3(1024 / 64, MROWS / 64), 256, 0, stream>>>(
        hb_bf, WT + 393216, fb1, nullptr, nullptr, f1_bf, MROWS, 1024, 256, 1024);

    // FFN2: f1 @ w2 + b2 + fused -> out fp32
    mgemm64<0><<<dim3(256 / 64, MROWS / 64), 256, 0, stream>>>(
        f1_bf, WT + 655360, fb2, fusedb, out, nullptr, MROWS, 256, 1024, 0);
}